// Round 1
// 933.690 us; speedup vs baseline: 1.1843x; 1.1843x over previous
//
#include <hip/hip_runtime.h>

typedef unsigned short u16;
typedef short short8v __attribute__((ext_vector_type(8)));
typedef float float4v __attribute__((ext_vector_type(4)));

__device__ __forceinline__ float b2f(u16 u) { return __uint_as_float(((unsigned)u) << 16); }
__device__ __forceinline__ u16 f2b(float f) {
    unsigned i = __float_as_uint(f);
    unsigned r = i + 0x7fffu + ((i >> 16) & 1u);
    return (u16)(r >> 16);
}
__device__ __forceinline__ float gelu_f(float x) {
    float x3 = x * x * x;
    return 0.5f * x * (1.0f + tanhf(0.7978845608028654f * (x + 0.044715f * x3)));
}

typedef const __attribute__((address_space(1))) unsigned int* gas_ptr;
typedef __attribute__((address_space(3))) unsigned int* las_ptr;
// async global->LDS, 16B per lane, dest = wave-uniform base + lane*16
__device__ __forceinline__ void gload16(const u16* g, u16* l) {
    __builtin_amdgcn_global_load_lds((gas_ptr)g, (las_ptr)l, 16, 0, 0);
}

// out[n*K + k] = bf16(in[k*N + n])   (fp32 weights -> bf16 transposed, k-contiguous)
__global__ void transpose_k(const float* __restrict__ in, u16* __restrict__ out, int K, int N) {
    int idx = blockIdx.x * 256 + threadIdx.x;
    if (idx < K * N) {
        int n = idx / K;
        int k = idx - n * K;
        out[idx] = f2b(in[(size_t)k * N + n]);
    }
}

// LN1 + cyclic shift(-3,-3) + window partition. One wave per windowed token (chunk-local).
__global__ __launch_bounds__(256) void ln1_win_kernel(
    const float* __restrict__ x, size_t tok0, const float* __restrict__ sc,
    const float* __restrict__ bi, u16* __restrict__ win) {
    int t = blockIdx.x * 4 + (threadIdx.x >> 6);
    int lane = threadIdx.x & 63;
    int wi = t / 49, p = t - wi * 49;
    int b = wi >> 6, w = wi & 63;
    int wr = w >> 3, wc = w & 7;
    int ii = p / 7, jj = p - ii * 7;
    int r = wr * 7 + ii + 3; if (r >= 56) r -= 56;
    int c = wc * 7 + jj + 3; if (c >= 56) c -= 56;
    size_t off = (tok0 + (size_t)(b * 3136 + r * 56 + c)) * 256 + lane * 4;
    float4 d = *(const float4*)(x + off);
    float v0 = d.x, v1 = d.y, v2 = d.z, v3 = d.w;
    float s = v0 + v1 + v2 + v3;
    float ss = v0 * v0 + v1 * v1 + v2 * v2 + v3 * v3;
#pragma unroll
    for (int o = 32; o; o >>= 1) { s += __shfl_xor(s, o, 64); ss += __shfl_xor(ss, o, 64); }
    float mu = s * (1.0f / 256.0f);
    float rs = rsqrtf(ss * (1.0f / 256.0f) - mu * mu + 1e-6f);
    float4 s4 = *(const float4*)(sc + lane * 4);
    float4 b4 = *(const float4*)(bi + lane * 4);
    ushort4 o4;
    o4.x = f2b((v0 - mu) * rs * s4.x + b4.x);
    o4.y = f2b((v1 - mu) * rs * s4.y + b4.y);
    o4.z = f2b((v2 - mu) * rs * s4.z + b4.z);
    o4.w = f2b((v3 - mu) * rs * s4.w + b4.w);
    *(ushort4*)(win + (size_t)t * 256 + lane * 4) = o4;
}

// C[M,N] = A[M,K] @ Bt[N,K]^T + bias(fp32), M-guarded. A/Bt bf16.
// EPI: 0 = bias (bf16 out), 1 = bias+gelu (bf16 out), 2 = bias+residual (FP32 out).
// Grid: blockIdx.x = n-tile (fast, shares A-panel), blockIdx.y = m-tile.
// m97 structure: linear LDS + global_load_lds(16B) staging, 2-barrier K-loop.
template <int EPI>
__global__ __launch_bounds__(256) void gemm_bt(
    const u16* __restrict__ A, const u16* __restrict__ Bt, const float* __restrict__ bias,
    const u16* __restrict__ res, void* __restrict__ Cout, int M, int N, int K) {
    // As[128*64] | Bs[128*64] during K-loop; reused as C-stage [128][136] in epilogue.
    __shared__ __align__(16) u16 smem[17408];  // 34816 B
    u16* As = smem;
    u16* Bs = smem + 8192;
    int tid = threadIdx.x;
    int m0 = blockIdx.y * 128, n0 = blockIdx.x * 128;
    int lane = tid & 63, wave = tid >> 6;
    int wm = (wave >> 1) * 64, wn = (wave & 1) * 64;
    int lrow = lane & 15, qd = lane >> 4;
    int c0 = wave << 2;          // this wave's first 1KB chunk (of 16)
    int rsub0 = lane >> 3;       // row within 8-row chunk
    int kc = (lane & 7) << 3;    // k-col (u16 units) within 64-wide tile
    float4v acc[4][4] = {};
    int kTiles = K >> 6;
    for (int kt = 0; kt < kTiles; ++kt) {
        int k0 = kt << 6;
#pragma unroll
        for (int i = 0; i < 4; ++i) {
            int c = c0 + i;                 // chunk 0..15 -> rows [c*8, c*8+8)
            int rsub = (c << 3) + rsub0;    // tile row 0..127
            int rA = m0 + rsub; if (rA >= M) rA = M - 1;  // clamp; store is guarded
            gload16(A + (size_t)rA * K + k0 + kc, As + (c << 9));
            gload16(Bt + (size_t)(n0 + rsub) * K + k0 + kc, Bs + (c << 9));
        }
        __syncthreads();   // drains vmcnt (compiler-inserted) before use
#pragma unroll
        for (int ks = 0; ks < 64; ks += 32) {
            short8v af[4], bfr[4];
#pragma unroll
            for (int mi = 0; mi < 4; ++mi)
                af[mi] = *(const short8v*)&As[(wm + mi * 16 + lrow) * 64 + ks + qd * 8];
#pragma unroll
            for (int ni = 0; ni < 4; ++ni)
                bfr[ni] = *(const short8v*)&Bs[(wn + ni * 16 + lrow) * 64 + ks + qd * 8];
#pragma unroll
            for (int mi = 0; mi < 4; ++mi)
#pragma unroll
                for (int ni = 0; ni < 4; ++ni)
                    acc[mi][ni] = __builtin_amdgcn_mfma_f32_16x16x32_bf16(
                        af[mi], bfr[ni], acc[mi][ni], 0, 0, 0);
        }
        __syncthreads();
    }
    if (EPI == 2) {
        // fp32 + residual scatter: 16 lanes x 4B = 64B row segments, txn-clean already.
#pragma unroll
        for (int ni = 0; ni < 4; ++ni) {
            int col = n0 + wn + ni * 16 + lrow;
            float bv = bias[col];
#pragma unroll
            for (int mi = 0; mi < 4; ++mi) {
#pragma unroll
                for (int rr = 0; rr < 4; ++rr) {
                    int row = m0 + wm + mi * 16 + qd * 4 + rr;
                    if (row < M) {
                        float v = acc[mi][ni][rr] + bv + b2f(res[(size_t)row * N + col]);
                        ((float*)Cout)[(size_t)row * N + col] = v;
                    }
                }
            }
        }
    } else {
        // bf16 out: transpose-stage via LDS (row stride 136 u16 = 272B: 16B-aligned,
        // write conflicts 2-way=free), then 16B coalesced stores.
#pragma unroll
        for (int ni = 0; ni < 4; ++ni) {
            float bv = bias[n0 + wn + ni * 16 + lrow];
#pragma unroll
            for (int mi = 0; mi < 4; ++mi) {
#pragma unroll
                for (int rr = 0; rr < 4; ++rr) {
                    float v = acc[mi][ni][rr] + bv;
                    if (EPI == 1) v = gelu_f(v);
                    smem[(wm + mi * 16 + qd * 4 + rr) * 136 + wn + ni * 16 + lrow] = f2b(v);
                }
            }
        }
        __syncthreads();
        u16* outp = (u16*)Cout;
#pragma unroll
        for (int j = 0; j < 8; ++j) {
            int slot = j * 256 + tid;          // 2048 slots of 8 u16
            int row = slot >> 4, cs = (slot & 15) << 3;
            short8v vv = *(const short8v*)&smem[row * 136 + cs];
            int grow = m0 + row;
            if (grow < M)
                *(short8v*)(outp + (size_t)grow * N + n0 + cs) = vv;
        }
    }
}

// One wave per (window-in-chunk, head). q in regs, k/v in LDS (fp32, broadcast reads).
__global__ __launch_bounds__(256) void attn_kernel(
    const u16* __restrict__ qkv, const float* __restrict__ btab, u16* __restrict__ attno) {
    __shared__ float kvs[4][2][49][32];  // 50176 B
    int wave = threadIdx.x >> 6, lane = threadIdx.x & 63;
    int u = blockIdx.x * 4 + wave;
    int wi = u >> 3, h = u & 7;
    int w = wi & 63;                      // window-within-batch (mask depends only on this)
    const u16* base = qkv + (size_t)wi * 49 * 768 + h * 32;
    for (int idx = lane; idx < 196; idx += 64) {
        int p = idx >> 2, part = (idx & 3) << 3;
        uint4 kd = *(const uint4*)(base + 256 + (size_t)p * 768 + part);
        uint4 vd = *(const uint4*)(base + 512 + (size_t)p * 768 + part);
        float* kp = &kvs[wave][0][p][part];
        float* vp = &kvs[wave][1][p][part];
        const unsigned* ku = (const unsigned*)&kd;
        const unsigned* vu = (const unsigned*)&vd;
#pragma unroll
        for (int i = 0; i < 4; ++i) {
            kp[2 * i] = __uint_as_float(ku[i] << 16);
            kp[2 * i + 1] = __uint_as_float(ku[i] & 0xffff0000u);
            vp[2 * i] = __uint_as_float(vu[i] << 16);
            vp[2 * i + 1] = __uint_as_float(vu[i] & 0xffff0000u);
        }
    }
    __syncthreads();
    int p = lane;
    if (p < 49) {
        float qreg[32];
        const u16* qp = base + (size_t)p * 768;
#pragma unroll
        for (int cq = 0; cq < 4; ++cq) {
            uint4 qd = *(const uint4*)(qp + cq * 8);
            const unsigned* qu = (const unsigned*)&qd;
#pragma unroll
            for (int i = 0; i < 4; ++i) {
                qreg[cq * 8 + 2 * i] = __uint_as_float(qu[i] << 16);
                qreg[cq * 8 + 2 * i + 1] = __uint_as_float(qu[i] & 0xffff0000u);
            }
        }
        int wrr = (w >> 3) * 7, wcc = (w & 7) * 7;
        int py = p / 7, px = p - py * 7;
        int rp = wrr + py, cp = wcc + px;
        int regp = (rp < 49 ? 0 : (rp < 53 ? 1 : 2)) * 3 + (cp < 49 ? 0 : (cp < 53 ? 1 : 2));
        float sreg[49];
        const float scale = 0.17677669529663687f;  // 32^-0.5
#pragma unroll
        for (int q = 0; q < 49; ++q) {
            const float4* krow = (const float4*)kvs[wave][0][q];
            float s = 0.f;
#pragma unroll
            for (int d4 = 0; d4 < 8; ++d4) {
                float4 kk = krow[d4];
                s += qreg[d4 * 4] * kk.x + qreg[d4 * 4 + 1] * kk.y +
                     qreg[d4 * 4 + 2] * kk.z + qreg[d4 * 4 + 3] * kk.w;
            }
            s *= scale;
            int qy = q / 7, qx = q - qy * 7;
            int ridx = (px - qx + 6) * 13 + (py - qy + 6);
            s += btab[ridx * 8 + h];
            int rq = wrr + qy, cq2 = wcc + qx;
            int regq = (rq < 49 ? 0 : (rq < 53 ? 1 : 2)) * 3 + (cq2 < 49 ? 0 : (cq2 < 53 ? 1 : 2));
            s += (regq != regp) ? -100.f : 0.f;
            sreg[q] = s;
        }
        float mx = sreg[0];
#pragma unroll
        for (int q = 1; q < 49; ++q) mx = fmaxf(mx, sreg[q]);
        float sum = 0.f;
#pragma unroll
        for (int q = 0; q < 49; ++q) { float e = __expf(sreg[q] - mx); sreg[q] = e; sum += e; }
        float inv = 1.0f / sum;
        float acc[32];
#pragma unroll
        for (int i = 0; i < 32; ++i) acc[i] = 0.f;
#pragma unroll
        for (int q = 0; q < 49; ++q) {
            float pv = sreg[q] * inv;
            const float4* vrow = (const float4*)kvs[wave][1][q];
#pragma unroll
            for (int d4 = 0; d4 < 8; ++d4) {
                float4 vv = vrow[d4];
                acc[d4 * 4] += pv * vv.x;
                acc[d4 * 4 + 1] += pv * vv.y;
                acc[d4 * 4 + 2] += pv * vv.z;
                acc[d4 * 4 + 3] += pv * vv.w;
            }
        }
        u16* op = attno + ((size_t)wi * 49 + p) * 256 + h * 32;
#pragma unroll
        for (int cq = 0; cq < 4; ++cq) {
            uint4 dd;
            unsigned* dp = (unsigned*)&dd;
#pragma unroll
            for (int i = 0; i < 4; ++i)
                dp[i] = (unsigned)f2b(acc[cq * 8 + 2 * i]) |
                        ((unsigned)f2b(acc[cq * 8 + 2 * i + 1]) << 16);
            *(uint4*)(op + cq * 8) = dd;
        }
    }
}

// window reverse + roll(+3,+3) + residual + LN2. One wave per natural token (chunk-local).
__global__ __launch_bounds__(256) void scatter_ln2_kernel(
    const float* __restrict__ x, size_t tok0, const u16* __restrict__ projo,
    const float* __restrict__ sc, const float* __restrict__ bi,
    u16* __restrict__ x2, u16* __restrict__ ln2o) {
    int tk = blockIdx.x * 4 + (threadIdx.x >> 6);
    int lane = threadIdx.x & 63;
    int b = tk / 3136, l = tk - b * 3136;
    int r = l / 56, c = l - r * 56;
    int r2 = r + 53; if (r2 >= 56) r2 -= 56;
    int c2 = c + 53; if (c2 >= 56) c2 -= 56;
    int wr = r2 / 7, ri = r2 - wr * 7;
    int wc = c2 / 7, ci = c2 - wc * 7;
    size_t t = ((size_t)(b * 64 + wr * 8 + wc)) * 49 + ri * 7 + ci;
    size_t loff = (size_t)tk * 256 + lane * 4;
    size_t goff = (tok0 + tk) * 256 + lane * 4;
    float4 xd = *(const float4*)(x + goff);
    ushort4 pd = *(const ushort4*)(projo + t * 256 + lane * 4);
    float v0 = xd.x + b2f(pd.x);
    float v1 = xd.y + b2f(pd.y);
    float v2 = xd.z + b2f(pd.z);
    float v3 = xd.w + b2f(pd.w);
    ushort4 o4;
    o4.x = f2b(v0); o4.y = f2b(v1); o4.z = f2b(v2); o4.w = f2b(v3);
    *(ushort4*)(x2 + loff) = o4;
    float s = v0 + v1 + v2 + v3;
    float ss = v0 * v0 + v1 * v1 + v2 * v2 + v3 * v3;
#pragma unroll
    for (int o = 32; o; o >>= 1) { s += __shfl_xor(s, o, 64); ss += __shfl_xor(ss, o, 64); }
    float mu = s * (1.0f / 256.0f);
    float rs = rsqrtf(ss * (1.0f / 256.0f) - mu * mu + 1e-6f);
    float4 s4 = *(const float4*)(sc + lane * 4);
    float4 b4 = *(const float4*)(bi + lane * 4);
    ushort4 n4;
    n4.x = f2b((v0 - mu) * rs * s4.x + b4.x);
    n4.y = f2b((v1 - mu) * rs * s4.y + b4.y);
    n4.z = f2b((v2 - mu) * rs * s4.z + b4.z);
    n4.w = f2b((v3 - mu) * rs * s4.w + b4.w);
    *(ushort4*)(ln2o + loff) = n4;
}

extern "C" void kernel_launch(void* const* d_in, const int* in_sizes, int n_in,
                              void* d_out, int out_size, void* d_ws, size_t ws_size,
                              hipStream_t stream) {
    const float* x     = (const float*)d_in[0];
    const float* ln1s  = (const float*)d_in[1];
    const float* ln1b  = (const float*)d_in[2];
    const float* qkvw  = (const float*)d_in[3];
    const float* qkvb  = (const float*)d_in[4];
    const float* projw = (const float*)d_in[5];
    const float* projb = (const float*)d_in[6];
    const float* btab  = (const float*)d_in[7];
    const float* ln2s  = (const float*)d_in[8];
    const float* ln2b  = (const float*)d_in[9];
    const float* fc1w  = (const float*)d_in[10];
    const float* fc1b  = (const float*)d_in[11];
    const float* fc2w  = (const float*)d_in[12];
    const float* fc2b  = (const float*)d_in[13];
    float* out = (float*)d_out;                 // FINAL OUTPUT IS FP32
    char* ws = (char*)d_ws;

    // ws: transposed bf16 weights (1.5 MB), then chunk regions.
    u16* wt_qkv  = (u16*)(ws + 0);        // 256x768^T   393216 B
    u16* wt_proj = (u16*)(ws + 393216);   // 256x256^T   131072 B
    u16* wt_fc1  = (u16*)(ws + 524288);   // 256x1024^T  524288 B
    u16* wt_fc2  = (u16*)(ws + 1048576);  // 1024x256^T  524288 B
    const size_t base = 1572864;

    transpose_k<<<768, 256, 0, stream>>>(qkvw, wt_qkv, 256, 768);
    transpose_k<<<256, 256, 0, stream>>>(projw, wt_proj, 256, 256);
    transpose_k<<<1024, 256, 0, stream>>>(fc1w, wt_fc1, 256, 1024);
    transpose_k<<<1024, 256, 0, stream>>>(fc2w, wt_fc2, 1024, 256);

    // chunk size NB (batches): footprint = base + T*3072 B, T = NB*3136 tokens.
    // NB=16 keeps per-chunk intermediates (~154 MB) L3-resident.
    int NB = 16;
    while (NB > 1 && base + (size_t)NB * 3136 * 3072 > ws_size) NB >>= 1;
    const size_t T = (size_t)NB * 3136;

    u16* regA = (u16*)(ws + base);                       // T*512  B: win -> attno -> ln2o
    u16* regB = (u16*)(ws + base + T * 512);             // T*2048 B: qkv -> projo -> mlph
    u16* regX = (u16*)(ws + base + T * 512 + T * 2048);  // T*512  B: x2 residual

    for (int c0 = 0; c0 < 32; c0 += NB) {
        size_t tok0 = (size_t)c0 * 3136;
        float* outc = out + tok0 * 256;
        int Mc = (int)T;
        int gx = (Mc + 127) / 128;

        ln1_win_kernel<<<Mc / 4, 256, 0, stream>>>(x, tok0, ln1s, ln1b, regA);
        gemm_bt<0><<<dim3(6, gx), 256, 0, stream>>>(regA, wt_qkv, qkvb, nullptr,
                                                    regB, Mc, 768, 256);
        attn_kernel<<<NB * 128, 256, 0, stream>>>(regB, btab, regA);
        gemm_bt<0><<<dim3(2, gx), 256, 0, stream>>>(regA, wt_proj, projb, nullptr,
                                                    regB, Mc, 256, 256);
        scatter_ln2_kernel<<<Mc / 4, 256, 0, stream>>>(x, tok0, regB, ln2s, ln2b,
                                                       regX, regA);
        gemm_bt<1><<<dim3(8, gx), 256, 0, stream>>>(regA, wt_fc1, fc1b, nullptr,
                                                    regB, Mc, 1024, 256);
        gemm_bt<2><<<dim3(2, gx), 256, 0, stream>>>(regB, wt_fc2, fc2b, regX,
                                                    outc, Mc, 256, 1024);
    }
}

// Round 2
// 886.162 us; speedup vs baseline: 1.2479x; 1.0536x over previous
//
#include <hip/hip_runtime.h>

typedef unsigned short u16;
typedef short short8v __attribute__((ext_vector_type(8)));
typedef float float4v __attribute__((ext_vector_type(4)));

__device__ __forceinline__ float b2f(u16 u) { return __uint_as_float(((unsigned)u) << 16); }
__device__ __forceinline__ u16 f2b(float f) {
    unsigned i = __float_as_uint(f);
    unsigned r = i + 0x7fffu + ((i >> 16) & 1u);
    return (u16)(r >> 16);
}
// tanh-gelu via hardware exp: 0.5x(1+tanh z) = x * (1 - 1/(e^{2z}+1)), exact identity.
__device__ __forceinline__ float gelu_f(float x) {
    float z2 = 1.5957691216057308f * (x + 0.044715f * x * x * x);  // 2*sqrt(2/pi)*(...)
    float e = __expf(z2);
    return x * (1.0f - 1.0f / (e + 1.0f));
}

typedef const __attribute__((address_space(1))) unsigned int* gas_ptr;
typedef __attribute__((address_space(3))) unsigned int* las_ptr;
// async global->LDS, 16B per lane, dest = wave-uniform base + lane*16
__device__ __forceinline__ void gload16(const u16* g, u16* l) {
    __builtin_amdgcn_global_load_lds((gas_ptr)g, (las_ptr)l, 16, 0, 0);
}

// out[n*K + k] = bf16(in[k*N + n])   (fp32 weights -> bf16 transposed, k-contiguous)
__global__ void transpose_k(const float* __restrict__ in, u16* __restrict__ out, int K, int N) {
    int idx = blockIdx.x * 256 + threadIdx.x;
    if (idx < K * N) {
        int n = idx / K;
        int k = idx - n * K;
        out[idx] = f2b(in[(size_t)k * N + n]);
    }
}

// LN1 + cyclic shift(-3,-3) + window partition. One wave per windowed token (chunk-local).
__global__ __launch_bounds__(256) void ln1_win_kernel(
    const float* __restrict__ x, size_t tok0, const float* __restrict__ sc,
    const float* __restrict__ bi, u16* __restrict__ win) {
    int t = blockIdx.x * 4 + (threadIdx.x >> 6);
    int lane = threadIdx.x & 63;
    int wi = t / 49, p = t - wi * 49;
    int b = wi >> 6, w = wi & 63;
    int wr = w >> 3, wc = w & 7;
    int ii = p / 7, jj = p - ii * 7;
    int r = wr * 7 + ii + 3; if (r >= 56) r -= 56;
    int c = wc * 7 + jj + 3; if (c >= 56) c -= 56;
    size_t off = (tok0 + (size_t)(b * 3136 + r * 56 + c)) * 256 + lane * 4;
    float4 d = *(const float4*)(x + off);
    float v0 = d.x, v1 = d.y, v2 = d.z, v3 = d.w;
    float s = v0 + v1 + v2 + v3;
    float ss = v0 * v0 + v1 * v1 + v2 * v2 + v3 * v3;
#pragma unroll
    for (int o = 32; o; o >>= 1) { s += __shfl_xor(s, o, 64); ss += __shfl_xor(ss, o, 64); }
    float mu = s * (1.0f / 256.0f);
    float rs = rsqrtf(ss * (1.0f / 256.0f) - mu * mu + 1e-6f);
    float4 s4 = *(const float4*)(sc + lane * 4);
    float4 b4 = *(const float4*)(bi + lane * 4);
    ushort4 o4;
    o4.x = f2b((v0 - mu) * rs * s4.x + b4.x);
    o4.y = f2b((v1 - mu) * rs * s4.y + b4.y);
    o4.z = f2b((v2 - mu) * rs * s4.z + b4.z);
    o4.w = f2b((v3 - mu) * rs * s4.w + b4.w);
    *(ushort4*)(win + (size_t)t * 256 + lane * 4) = o4;
}

// C[M,N] = A[M,K] @ Bt[N,K]^T + bias(fp32), M-guarded. A/Bt bf16.
// EPI: 0 = bias (bf16 out), 1 = bias+gelu (bf16 out), 2 = bias+residual (FP32 out).
// Grid: blockIdx.x = n-tile (fast, shares A-panel), blockIdx.y = m-tile.
// LDS: linear dest (global_load_lds requirement) + XOR-swizzled SOURCE slot +
// matching XOR on the read (rule #21: both-sides-or-neither). Kills the 16-way
// ds_read_b128 bank conflict of stride-128B rows.
template <int EPI>
__global__ __launch_bounds__(256) void gemm_bt(
    const u16* __restrict__ A, const u16* __restrict__ Bt, const float* __restrict__ bias,
    const u16* __restrict__ res, void* __restrict__ Cout, int M, int N, int K) {
    // As[128*64] | Bs[128*64] during K-loop; reused as C-stage [128][136] in epilogue.
    __shared__ __align__(16) u16 smem[17408];  // 34816 B
    u16* As = smem;
    u16* Bs = smem + 8192;
    int tid = threadIdx.x;
    int m0 = blockIdx.y * 128, n0 = blockIdx.x * 128;
    int lane = tid & 63, wave = tid >> 6;
    int wm = (wave >> 1) * 64, wn = (wave & 1) * 64;
    int lrow = lane & 15, qd = lane >> 4;
    int c0 = wave << 2;          // this wave's first 1KB chunk (of 16)
    int rsub0 = lane >> 3;       // row within 8-row chunk (== row&7 of the dest row)
    // swizzled source slot: LDS[row][s] receives G[row][s ^ (row&7)]
    int kc = (((lane & 7) ^ rsub0) << 3);    // k-col (u16) within 64-wide tile, swizzled
    float4v acc[4][4] = {};
    int kTiles = K >> 6;
    for (int kt = 0; kt < kTiles; ++kt) {
        int k0 = kt << 6;
#pragma unroll
        for (int i = 0; i < 4; ++i) {
            int c = c0 + i;                 // chunk 0..15 -> rows [c*8, c*8+8)
            int rsub = (c << 3) + rsub0;    // tile row 0..127
            int rA = m0 + rsub; if (rA >= M) rA = M - 1;  // clamp; store is guarded
            gload16(A + (size_t)rA * K + k0 + kc, As + (c << 9));
            gload16(Bt + (size_t)(n0 + rsub) * K + k0 + kc, Bs + (c << 9));
        }
        __syncthreads();   // drains vmcnt (compiler-inserted) before use
#pragma unroll
        for (int ks = 0; ks < 64; ks += 32) {
            short8v af[4], bfr[4];
#pragma unroll
            for (int mi = 0; mi < 4; ++mi) {
                int row = wm + mi * 16 + lrow;
                int s = ((ks >> 3) + qd) ^ (row & 7);          // read-side XOR
                af[mi] = *(const short8v*)&As[row * 64 + (s << 3)];
            }
#pragma unroll
            for (int ni = 0; ni < 4; ++ni) {
                int row = wn + ni * 16 + lrow;
                int s = ((ks >> 3) + qd) ^ (row & 7);
                bfr[ni] = *(const short8v*)&Bs[row * 64 + (s << 3)];
            }
#pragma unroll
            for (int mi = 0; mi < 4; ++mi)
#pragma unroll
                for (int ni = 0; ni < 4; ++ni)
                    acc[mi][ni] = __builtin_amdgcn_mfma_f32_16x16x32_bf16(
                        af[mi], bfr[ni], acc[mi][ni], 0, 0, 0);
        }
        __syncthreads();
    }
    if (EPI == 2) {
        // fp32 + residual scatter: 16 lanes x 4B = 64B row segments, txn-clean already.
#pragma unroll
        for (int ni = 0; ni < 4; ++ni) {
            int col = n0 + wn + ni * 16 + lrow;
            float bv = bias[col];
#pragma unroll
            for (int mi = 0; mi < 4; ++mi) {
#pragma unroll
                for (int rr = 0; rr < 4; ++rr) {
                    int row = m0 + wm + mi * 16 + qd * 4 + rr;
                    if (row < M) {
                        float v = acc[mi][ni][rr] + bv + b2f(res[(size_t)row * N + col]);
                        ((float*)Cout)[(size_t)row * N + col] = v;
                    }
                }
            }
        }
    } else {
        // bf16 out: transpose-stage via LDS (row stride 136 u16 = 272B: 16B-aligned,
        // write conflicts 2-way=free), then 16B coalesced stores.
#pragma unroll
        for (int ni = 0; ni < 4; ++ni) {
            float bv = bias[n0 + wn + ni * 16 + lrow];
#pragma unroll
            for (int mi = 0; mi < 4; ++mi) {
#pragma unroll
                for (int rr = 0; rr < 4; ++rr) {
                    float v = acc[mi][ni][rr] + bv;
                    if (EPI == 1) v = gelu_f(v);
                    smem[(wm + mi * 16 + qd * 4 + rr) * 136 + wn + ni * 16 + lrow] = f2b(v);
                }
            }
        }
        __syncthreads();
        u16* outp = (u16*)Cout;
#pragma unroll
        for (int j = 0; j < 8; ++j) {
            int slot = j * 256 + tid;          // 2048 slots of 8 u16
            int row = slot >> 4, cs = (slot & 15) << 3;
            short8v vv = *(const short8v*)&smem[row * 136 + cs];
            int grow = m0 + row;
            if (grow < M)
                *(short8v*)(outp + (size_t)grow * N + n0 + cs) = vv;
        }
    }
}

// One wave per (window-in-chunk, head). q in regs, k/v in LDS (fp32, broadcast reads).
__global__ __launch_bounds__(256) void attn_kernel(
    const u16* __restrict__ qkv, const float* __restrict__ btab, u16* __restrict__ attno) {
    __shared__ float kvs[4][2][49][32];  // 50176 B
    int wave = threadIdx.x >> 6, lane = threadIdx.x & 63;
    int u = blockIdx.x * 4 + wave;
    int wi = u >> 3, h = u & 7;
    int w = wi & 63;                      // window-within-batch (mask depends only on this)
    const u16* base = qkv + (size_t)wi * 49 * 768 + h * 32;
    for (int idx = lane; idx < 196; idx += 64) {
        int p = idx >> 2, part = (idx & 3) << 3;
        uint4 kd = *(const uint4*)(base + 256 + (size_t)p * 768 + part);
        uint4 vd = *(const uint4*)(base + 512 + (size_t)p * 768 + part);
        float* kp = &kvs[wave][0][p][part];
        float* vp = &kvs[wave][1][p][part];
        const unsigned* ku = (const unsigned*)&kd;
        const unsigned* vu = (const unsigned*)&vd;
#pragma unroll
        for (int i = 0; i < 4; ++i) {
            kp[2 * i] = __uint_as_float(ku[i] << 16);
            kp[2 * i + 1] = __uint_as_float(ku[i] & 0xffff0000u);
            vp[2 * i] = __uint_as_float(vu[i] << 16);
            vp[2 * i + 1] = __uint_as_float(vu[i] & 0xffff0000u);
        }
    }
    __syncthreads();
    int p = lane;
    if (p < 49) {
        float qreg[32];
        const u16* qp = base + (size_t)p * 768;
#pragma unroll
        for (int cq = 0; cq < 4; ++cq) {
            uint4 qd = *(const uint4*)(qp + cq * 8);
            const unsigned* qu = (const unsigned*)&qd;
#pragma unroll
            for (int i = 0; i < 4; ++i) {
                qreg[cq * 8 + 2 * i] = __uint_as_float(qu[i] << 16);
                qreg[cq * 8 + 2 * i + 1] = __uint_as_float(qu[i] & 0xffff0000u);
            }
        }
        int wrr = (w >> 3) * 7, wcc = (w & 7) * 7;
        int py = p / 7, px = p - py * 7;
        int rp = wrr + py, cp = wcc + px;
        int regp = (rp < 49 ? 0 : (rp < 53 ? 1 : 2)) * 3 + (cp < 49 ? 0 : (cp < 53 ? 1 : 2));
        float sreg[49];
        const float scale = 0.17677669529663687f;  // 32^-0.5
#pragma unroll
        for (int q = 0; q < 49; ++q) {
            const float4* krow = (const float4*)kvs[wave][0][q];
            float s = 0.f;
#pragma unroll
            for (int d4 = 0; d4 < 8; ++d4) {
                float4 kk = krow[d4];
                s += qreg[d4 * 4] * kk.x + qreg[d4 * 4 + 1] * kk.y +
                     qreg[d4 * 4 + 2] * kk.z + qreg[d4 * 4 + 3] * kk.w;
            }
            s *= scale;
            int qy = q / 7, qx = q - qy * 7;
            int ridx = (px - qx + 6) * 13 + (py - qy + 6);
            s += btab[ridx * 8 + h];
            int rq = wrr + qy, cq2 = wcc + qx;
            int regq = (rq < 49 ? 0 : (rq < 53 ? 1 : 2)) * 3 + (cq2 < 49 ? 0 : (cq2 < 53 ? 1 : 2));
            s += (regq != regp) ? -100.f : 0.f;
            sreg[q] = s;
        }
        float mx = sreg[0];
#pragma unroll
        for (int q = 1; q < 49; ++q) mx = fmaxf(mx, sreg[q]);
        float sum = 0.f;
#pragma unroll
        for (int q = 0; q < 49; ++q) { float e = __expf(sreg[q] - mx); sreg[q] = e; sum += e; }
        float inv = 1.0f / sum;
        float acc[32];
#pragma unroll
        for (int i = 0; i < 32; ++i) acc[i] = 0.f;
#pragma unroll
        for (int q = 0; q < 49; ++q) {
            float pv = sreg[q] * inv;
            const float4* vrow = (const float4*)kvs[wave][1][q];
#pragma unroll
            for (int d4 = 0; d4 < 8; ++d4) {
                float4 vv = vrow[d4];
                acc[d4 * 4] += pv * vv.x;
                acc[d4 * 4 + 1] += pv * vv.y;
                acc[d4 * 4 + 2] += pv * vv.z;
                acc[d4 * 4 + 3] += pv * vv.w;
            }
        }
        u16* op = attno + ((size_t)wi * 49 + p) * 256 + h * 32;
#pragma unroll
        for (int cq = 0; cq < 4; ++cq) {
            uint4 dd;
            unsigned* dp = (unsigned*)&dd;
#pragma unroll
            for (int i = 0; i < 4; ++i)
                dp[i] = (unsigned)f2b(acc[cq * 8 + 2 * i]) |
                        ((unsigned)f2b(acc[cq * 8 + 2 * i + 1]) << 16);
            *(uint4*)(op + cq * 8) = dd;
        }
    }
}

// window reverse + roll(+3,+3) + residual + LN2. One wave per natural token (chunk-local).
__global__ __launch_bounds__(256) void scatter_ln2_kernel(
    const float* __restrict__ x, size_t tok0, const u16* __restrict__ projo,
    const float* __restrict__ sc, const float* __restrict__ bi,
    u16* __restrict__ x2, u16* __restrict__ ln2o) {
    int tk = blockIdx.x * 4 + (threadIdx.x >> 6);
    int lane = threadIdx.x & 63;
    int b = tk / 3136, l = tk - b * 3136;
    int r = l / 56, c = l - r * 56;
    int r2 = r + 53; if (r2 >= 56) r2 -= 56;
    int c2 = c + 53; if (c2 >= 56) c2 -= 56;
    int wr = r2 / 7, ri = r2 - wr * 7;
    int wc = c2 / 7, ci = c2 - wc * 7;
    size_t t = ((size_t)(b * 64 + wr * 8 + wc)) * 49 + ri * 7 + ci;
    size_t loff = (size_t)tk * 256 + lane * 4;
    size_t goff = (tok0 + tk) * 256 + lane * 4;
    float4 xd = *(const float4*)(x + goff);
    ushort4 pd = *(const ushort4*)(projo + t * 256 + lane * 4);
    float v0 = xd.x + b2f(pd.x);
    float v1 = xd.y + b2f(pd.y);
    float v2 = xd.z + b2f(pd.z);
    float v3 = xd.w + b2f(pd.w);
    ushort4 o4;
    o4.x = f2b(v0); o4.y = f2b(v1); o4.z = f2b(v2); o4.w = f2b(v3);
    *(ushort4*)(x2 + loff) = o4;
    float s = v0 + v1 + v2 + v3;
    float ss = v0 * v0 + v1 * v1 + v2 * v2 + v3 * v3;
#pragma unroll
    for (int o = 32; o; o >>= 1) { s += __shfl_xor(s, o, 64); ss += __shfl_xor(ss, o, 64); }
    float mu = s * (1.0f / 256.0f);
    float rs = rsqrtf(ss * (1.0f / 256.0f) - mu * mu + 1e-6f);
    float4 s4 = *(const float4*)(sc + lane * 4);
    float4 b4 = *(const float4*)(bi + lane * 4);
    ushort4 n4;
    n4.x = f2b((v0 - mu) * rs * s4.x + b4.x);
    n4.y = f2b((v1 - mu) * rs * s4.y + b4.y);
    n4.z = f2b((v2 - mu) * rs * s4.z + b4.z);
    n4.w = f2b((v3 - mu) * rs * s4.w + b4.w);
    *(ushort4*)(ln2o + loff) = n4;
}

extern "C" void kernel_launch(void* const* d_in, const int* in_sizes, int n_in,
                              void* d_out, int out_size, void* d_ws, size_t ws_size,
                              hipStream_t stream) {
    const float* x     = (const float*)d_in[0];
    const float* ln1s  = (const float*)d_in[1];
    const float* ln1b  = (const float*)d_in[2];
    const float* qkvw  = (const float*)d_in[3];
    const float* qkvb  = (const float*)d_in[4];
    const float* projw = (const float*)d_in[5];
    const float* projb = (const float*)d_in[6];
    const float* btab  = (const float*)d_in[7];
    const float* ln2s  = (const float*)d_in[8];
    const float* ln2b  = (const float*)d_in[9];
    const float* fc1w  = (const float*)d_in[10];
    const float* fc1b  = (const float*)d_in[11];
    const float* fc2w  = (const float*)d_in[12];
    const float* fc2b  = (const float*)d_in[13];
    float* out = (float*)d_out;                 // FINAL OUTPUT IS FP32
    char* ws = (char*)d_ws;

    // ws: transposed bf16 weights (1.5 MB), then chunk regions.
    u16* wt_qkv  = (u16*)(ws + 0);        // 256x768^T   393216 B
    u16* wt_proj = (u16*)(ws + 393216);   // 256x256^T   131072 B
    u16* wt_fc1  = (u16*)(ws + 524288);   // 256x1024^T  524288 B
    u16* wt_fc2  = (u16*)(ws + 1048576);  // 1024x256^T  524288 B
    const size_t base = 1572864;

    transpose_k<<<768, 256, 0, stream>>>(qkvw, wt_qkv, 256, 768);
    transpose_k<<<256, 256, 0, stream>>>(projw, wt_proj, 256, 256);
    transpose_k<<<1024, 256, 0, stream>>>(fc1w, wt_fc1, 256, 1024);
    transpose_k<<<1024, 256, 0, stream>>>(fc2w, wt_fc2, 1024, 256);

    // chunk size NB (batches): footprint = base + T*3072 B, T = NB*3136 tokens.
    // NB=16 keeps per-chunk intermediates (~154 MB) L3-resident.
    int NB = 16;
    while (NB > 1 && base + (size_t)NB * 3136 * 3072 > ws_size) NB >>= 1;
    const size_t T = (size_t)NB * 3136;

    u16* regA = (u16*)(ws + base);                       // T*512  B: win -> attno -> ln2o
    u16* regB = (u16*)(ws + base + T * 512);             // T*2048 B: qkv -> projo -> mlph
    u16* regX = (u16*)(ws + base + T * 512 + T * 2048);  // T*512  B: x2 residual

    for (int c0 = 0; c0 < 32; c0 += NB) {
        size_t tok0 = (size_t)c0 * 3136;
        float* outc = out + tok0 * 256;
        int Mc = (int)T;
        int gx = (Mc + 127) / 128;

        ln1_win_kernel<<<Mc / 4, 256, 0, stream>>>(x, tok0, ln1s, ln1b, regA);
        gemm_bt<0><<<dim3(6, gx), 256, 0, stream>>>(regA, wt_qkv, qkvb, nullptr,
                                                    regB, Mc, 768, 256);
        attn_kernel<<<NB * 128, 256, 0, stream>>>(regB, btab, regA);
        gemm_bt<0><<<dim3(2, gx), 256, 0, stream>>>(regA, wt_proj, projb, nullptr,
                                                    regB, Mc, 256, 256);
        scatter_ln2_kernel<<<Mc / 4, 256, 0, stream>>>(x, tok0, regB, ln2s, ln2b,
                                                       regX, regA);
        gemm_bt<1><<<dim3(8, gx), 256, 0, stream>>>(regA, wt_fc1, fc1b, nullptr,
                                                    regB, Mc, 1024, 256);
        gemm_bt<2><<<dim3(2, gx), 256, 0, stream>>>(regB, wt_fc2, fc2b, regX,
                                                    outc, Mc, 256, 1024);
    }
}

// Round 3
// 802.314 us; speedup vs baseline: 1.3783x; 1.1045x over previous
//
#include <hip/hip_runtime.h>

typedef unsigned short u16;
typedef short short8v __attribute__((ext_vector_type(8)));
typedef float float4v __attribute__((ext_vector_type(4)));

__device__ __forceinline__ float b2f(u16 u) { return __uint_as_float(((unsigned)u) << 16); }
__device__ __forceinline__ u16 f2b(float f) {
    unsigned i = __float_as_uint(f);
    unsigned r = i + 0x7fffu + ((i >> 16) & 1u);
    return (u16)(r >> 16);
}
// tanh-gelu via hardware exp: 0.5x(1+tanh z) = x * (1 - 1/(e^{2z}+1)), exact identity.
__device__ __forceinline__ float gelu_f(float x) {
    float z2 = 1.5957691216057308f * (x + 0.044715f * x * x * x);  // 2*sqrt(2/pi)*(...)
    float e = __expf(z2);
    return x * (1.0f - 1.0f / (e + 1.0f));
}

typedef const __attribute__((address_space(1))) unsigned int* gas_ptr;
typedef __attribute__((address_space(3))) unsigned int* las_ptr;
// async global->LDS, 16B per lane, dest = wave-uniform base + lane*16
__device__ __forceinline__ void gload16(const u16* g, u16* l) {
    __builtin_amdgcn_global_load_lds((gas_ptr)g, (las_ptr)l, 16, 0, 0);
}

// out[n*K + k] = bf16(in[k*N + n])   (fp32 weights -> bf16 transposed, k-contiguous)
__global__ void transpose_k(const float* __restrict__ in, u16* __restrict__ out, int K, int N) {
    int idx = blockIdx.x * 256 + threadIdx.x;
    if (idx < K * N) {
        int n = idx / K;
        int k = idx - n * K;
        out[idx] = f2b(in[(size_t)k * N + n]);
    }
}

// Precompute Sadd[type][h][64][64] bf16: rel-pos bias + shift mask + key padding.
// type bit1 = (window row == 7), bit0 = (window col == 7). Keys>=49 => -1e30.
__global__ void build_sadd(const float* __restrict__ btab, u16* __restrict__ tbl) {
    int idx = blockIdx.x * 256 + threadIdx.x;  // 4*8*64*64 = 131072
    int key = idx & 63;
    int q = (idx >> 6) & 63;
    int h = (idx >> 12) & 7;
    int type = idx >> 15;
    float v;
    if (key >= 49 || q >= 49) {
        v = -1e30f;
    } else {
        int qy = q / 7, qx = q - qy * 7;      // query token coords
        int ky = key / 7, kx = key - ky * 7;  // key token coords
        int ridx = (qx - kx + 6) * 13 + (qy - ky + 6);
        v = btab[ridx * 8 + h];
        int rcq = (type & 2) ? (qy < 4 ? 1 : 2) : 0;
        int ccq = (type & 1) ? (qx < 4 ? 1 : 2) : 0;
        int rck = (type & 2) ? (ky < 4 ? 1 : 2) : 0;
        int cck = (type & 1) ? (kx < 4 ? 1 : 2) : 0;
        if (rcq * 3 + ccq != rck * 3 + cck) v += -100.0f;
    }
    tbl[idx] = f2b(v);
}

// LN1 + cyclic shift(-3,-3) + window partition. One wave per windowed token (chunk-local).
__global__ __launch_bounds__(256) void ln1_win_kernel(
    const float* __restrict__ x, size_t tok0, const float* __restrict__ sc,
    const float* __restrict__ bi, u16* __restrict__ win) {
    int t = blockIdx.x * 4 + (threadIdx.x >> 6);
    int lane = threadIdx.x & 63;
    int wi = t / 49, p = t - wi * 49;
    int b = wi >> 6, w = wi & 63;
    int wr = w >> 3, wc = w & 7;
    int ii = p / 7, jj = p - ii * 7;
    int r = wr * 7 + ii + 3; if (r >= 56) r -= 56;
    int c = wc * 7 + jj + 3; if (c >= 56) c -= 56;
    size_t off = (tok0 + (size_t)(b * 3136 + r * 56 + c)) * 256 + lane * 4;
    float4 d = *(const float4*)(x + off);
    float v0 = d.x, v1 = d.y, v2 = d.z, v3 = d.w;
    float s = v0 + v1 + v2 + v3;
    float ss = v0 * v0 + v1 * v1 + v2 * v2 + v3 * v3;
#pragma unroll
    for (int o = 32; o; o >>= 1) { s += __shfl_xor(s, o, 64); ss += __shfl_xor(ss, o, 64); }
    float mu = s * (1.0f / 256.0f);
    float rs = rsqrtf(ss * (1.0f / 256.0f) - mu * mu + 1e-6f);
    float4 s4 = *(const float4*)(sc + lane * 4);
    float4 b4 = *(const float4*)(bi + lane * 4);
    ushort4 o4;
    o4.x = f2b((v0 - mu) * rs * s4.x + b4.x);
    o4.y = f2b((v1 - mu) * rs * s4.y + b4.y);
    o4.z = f2b((v2 - mu) * rs * s4.z + b4.z);
    o4.w = f2b((v3 - mu) * rs * s4.w + b4.w);
    *(ushort4*)(win + (size_t)t * 256 + lane * 4) = o4;
}

// C[M,N] = A[M,K] @ Bt[N,K]^T + bias(fp32), M-guarded. A/Bt bf16.
// EPI: 0 = bias (bf16 out), 1 = bias+gelu (bf16 out), 2 = bias+residual (FP32 out).
// Grid: blockIdx.x = n-tile (fast, shares A-panel), blockIdx.y = m-tile.
template <int EPI>
__global__ __launch_bounds__(256) void gemm_bt(
    const u16* __restrict__ A, const u16* __restrict__ Bt, const float* __restrict__ bias,
    const u16* __restrict__ res, void* __restrict__ Cout, int M, int N, int K) {
    __shared__ __align__(16) u16 smem[17408];  // 34816 B
    u16* As = smem;
    u16* Bs = smem + 8192;
    int tid = threadIdx.x;
    int m0 = blockIdx.y * 128, n0 = blockIdx.x * 128;
    int lane = tid & 63, wave = tid >> 6;
    int wm = (wave >> 1) * 64, wn = (wave & 1) * 64;
    int lrow = lane & 15, qd = lane >> 4;
    int c0 = wave << 2;
    int rsub0 = lane >> 3;
    int kc = (((lane & 7) ^ rsub0) << 3);    // swizzled source slot
    float4v acc[4][4] = {};
    int kTiles = K >> 6;
    for (int kt = 0; kt < kTiles; ++kt) {
        int k0 = kt << 6;
#pragma unroll
        for (int i = 0; i < 4; ++i) {
            int c = c0 + i;
            int rsub = (c << 3) + rsub0;
            int rA = m0 + rsub; if (rA >= M) rA = M - 1;
            gload16(A + (size_t)rA * K + k0 + kc, As + (c << 9));
            gload16(Bt + (size_t)(n0 + rsub) * K + k0 + kc, Bs + (c << 9));
        }
        __syncthreads();
#pragma unroll
        for (int ks = 0; ks < 64; ks += 32) {
            short8v af[4], bfr[4];
#pragma unroll
            for (int mi = 0; mi < 4; ++mi) {
                int row = wm + mi * 16 + lrow;
                int s = ((ks >> 3) + qd) ^ (row & 7);
                af[mi] = *(const short8v*)&As[row * 64 + (s << 3)];
            }
#pragma unroll
            for (int ni = 0; ni < 4; ++ni) {
                int row = wn + ni * 16 + lrow;
                int s = ((ks >> 3) + qd) ^ (row & 7);
                bfr[ni] = *(const short8v*)&Bs[row * 64 + (s << 3)];
            }
#pragma unroll
            for (int mi = 0; mi < 4; ++mi)
#pragma unroll
                for (int ni = 0; ni < 4; ++ni)
                    acc[mi][ni] = __builtin_amdgcn_mfma_f32_16x16x32_bf16(
                        af[mi], bfr[ni], acc[mi][ni], 0, 0, 0);
        }
        __syncthreads();
    }
    if (EPI == 2) {
#pragma unroll
        for (int ni = 0; ni < 4; ++ni) {
            int col = n0 + wn + ni * 16 + lrow;
            float bv = bias[col];
#pragma unroll
            for (int mi = 0; mi < 4; ++mi) {
#pragma unroll
                for (int rr = 0; rr < 4; ++rr) {
                    int row = m0 + wm + mi * 16 + qd * 4 + rr;
                    if (row < M) {
                        float v = acc[mi][ni][rr] + bv + b2f(res[(size_t)row * N + col]);
                        ((float*)Cout)[(size_t)row * N + col] = v;
                    }
                }
            }
        }
    } else {
#pragma unroll
        for (int ni = 0; ni < 4; ++ni) {
            float bv = bias[n0 + wn + ni * 16 + lrow];
#pragma unroll
            for (int mi = 0; mi < 4; ++mi) {
#pragma unroll
                for (int rr = 0; rr < 4; ++rr) {
                    float v = acc[mi][ni][rr] + bv;
                    if (EPI == 1) v = gelu_f(v);
                    smem[(wm + mi * 16 + qd * 4 + rr) * 136 + wn + ni * 16 + lrow] = f2b(v);
                }
            }
        }
        __syncthreads();
        u16* outp = (u16*)Cout;
#pragma unroll
        for (int j = 0; j < 8; ++j) {
            int slot = j * 256 + tid;
            int row = slot >> 4, cs = (slot & 15) << 3;
            short8v vv = *(const short8v*)&smem[row * 136 + cs];
            int grow = m0 + row;
            if (grow < M)
                *(short8v*)(outp + (size_t)grow * N + n0 + cs) = vv;
        }
    }
}

// MFMA attention. One wave per (window, head); barrier-free (wave-private LDS).
// S = Q K^T via 16 mfma_16x16x32 (d=32 = one K-step); softmax in C-layout;
// P (bf16, unnormalized) + V^T staged in swizzled LDS; O^T = V^T P^T via 16 mfma;
// 1/rowsum applied at the output.
__global__ __launch_bounds__(256) void attn_kernel(
    const u16* __restrict__ qkv, const u16* __restrict__ sadd, u16* __restrict__ attno) {
    // per wave: P[64][64] u16 swz (8192B) | Vt[32][64] u16 swz (4096B) | sums[64] f32 (256B)
    __shared__ __align__(16) u16 lds[4][6272];  // 50176 B total
    int wave = threadIdx.x >> 6, lane = threadIdx.x & 63;
    u16* Plds = lds[wave];
    u16* Vt = lds[wave] + 4096;
    float* sums = (float*)(lds[wave] + 6144);
    int u = blockIdx.x * 4 + wave;
    int wi = u >> 3, h = u & 7;
    int w = wi & 63;
    int type = (((w >> 3) == 7) ? 2 : 0) | (((w & 7) == 7) ? 1 : 0);
    const u16* base = qkv + (size_t)wi * 49 * 768 + h * 32;
    int lrow = lane & 15, qd = lane >> 4;

    // zero Vt (padded tokens 49..63 must not contain NaN bits), then stage V^T swizzled.
#pragma unroll
    for (int z = 0; z < 4; ++z)
        *(short8v*)&Vt[(z * 64 + lane) * 8] = (short8v){0, 0, 0, 0, 0, 0, 0, 0};
    for (int idx = lane; idx < 196; idx += 64) {
        int t = idx >> 2, part = (idx & 3) << 3;
        uint4 vd = *(const uint4*)(base + 512 + (size_t)t * 768 + part);
        const u16* vs = (const u16*)&vd;
#pragma unroll
        for (int e = 0; e < 8; ++e) {
            int c = part + e;
            Vt[c * 64 + ((((t >> 3) ^ (c & 7)) << 3) | (t & 7))] = vs[e];
        }
    }

    // Q,K fragments straight from global (token-major == fragment layout).
    short8v qf[4], kf[4];
#pragma unroll
    for (int i = 0; i < 4; ++i) {
        qf[i] = *(const short8v*)(base + (size_t)(16 * i + lrow) * 768 + qd * 8);
        kf[i] = *(const short8v*)(base + 256 + (size_t)(16 * i + lrow) * 768 + qd * 8);
    }
    float4v s[4][4];
#pragma unroll
    for (int i = 0; i < 4; ++i)
#pragma unroll
        for (int j = 0; j < 4; ++j)
            s[i][j] = __builtin_amdgcn_mfma_f32_16x16x32_bf16(
                qf[i], kf[j], (float4v){0.f, 0.f, 0.f, 0.f}, 0, 0, 0);

    // scale + bias/mask table; padded-key tile overwritten (kills inf/NaN).
    const float scale = 0.17677669529663687f;  // 32^-0.5
    const u16* tb = sadd + ((size_t)(type * 8 + h) << 12);
#pragma unroll
    for (int i = 0; i < 4; ++i)
#pragma unroll
        for (int j = 0; j < 4; ++j)
#pragma unroll
            for (int rr = 0; rr < 4; ++rr) {
                int q = 16 * i + qd * 4 + rr, key = 16 * j + lrow;
                float v = s[i][j][rr] * scale + b2f(tb[q * 64 + key]);
                if (j == 3 && lrow > 0) v = -1e30f;
                s[i][j][rr] = v;
            }
    // row max (over j-tiles, then 16-lane column group)
    float rmx[4][4];
#pragma unroll
    for (int i = 0; i < 4; ++i)
#pragma unroll
        for (int rr = 0; rr < 4; ++rr) {
            float m = fmaxf(fmaxf(s[i][0][rr], s[i][1][rr]), fmaxf(s[i][2][rr], s[i][3][rr]));
#pragma unroll
            for (int o = 1; o < 16; o <<= 1) m = fmaxf(m, __shfl_xor(m, o, 64));
            rmx[i][rr] = m;
        }
    // exp, row sum, write P (bf16, unnormalized) swizzled
    int hi = lrow >> 3, lo = lrow & 7;
#pragma unroll
    for (int i = 0; i < 4; ++i)
#pragma unroll
        for (int rr = 0; rr < 4; ++rr) {
            int q = 16 * i + qd * 4 + rr;
            float e0 = __expf(s[i][0][rr] - rmx[i][rr]);
            float e1 = __expf(s[i][1][rr] - rmx[i][rr]);
            float e2 = __expf(s[i][2][rr] - rmx[i][rr]);
            float e3 = __expf(s[i][3][rr] - rmx[i][rr]);
            float sm = (e0 + e1) + (e2 + e3);
#pragma unroll
            for (int o = 1; o < 16; o <<= 1) sm += __shfl_xor(sm, o, 64);
            int q64 = q * 64, q7 = q & 7;
            Plds[q64 + ((((0 + hi) ^ q7) << 3) | lo)] = f2b(e0);
            Plds[q64 + ((((2 + hi) ^ q7) << 3) | lo)] = f2b(e1);
            Plds[q64 + ((((4 + hi) ^ q7) << 3) | lo)] = f2b(e2);
            Plds[q64 + ((((6 + hi) ^ q7) << 3) | lo)] = f2b(e3);
            if (lrow == 0) sums[q] = sm;
        }

    // O^T = V^T @ P^T : A-frag = Vt rows (channels), B-frag = P rows (queries as cols).
    float4v o[2][4] = {};
#pragma unroll
    for (int ks = 0; ks < 2; ++ks) {
        short8v av[2], bp[4];
#pragma unroll
        for (int ci = 0; ci < 2; ++ci) {
            int c = 16 * ci + lrow;
            av[ci] = *(const short8v*)&Vt[c * 64 + ((((ks << 2) + qd) ^ (c & 7)) << 3)];
        }
#pragma unroll
        for (int qj = 0; qj < 4; ++qj) {
            int q = 16 * qj + lrow;
            bp[qj] = *(const short8v*)&Plds[q * 64 + ((((ks << 2) + qd) ^ (q & 7)) << 3)];
        }
#pragma unroll
        for (int ci = 0; ci < 2; ++ci)
#pragma unroll
            for (int qj = 0; qj < 4; ++qj)
                o[ci][qj] = __builtin_amdgcn_mfma_f32_16x16x32_bf16(
                    av[ci], bp[qj], o[ci][qj], 0, 0, 0);
    }
    // normalize rows by 1/sum and store: O^T[c][q] -> attno[token q][h*32 + c]
#pragma unroll
    for (int qj = 0; qj < 4; ++qj) {
        int q = 16 * qj + lrow;
        if (q < 49) {
            float inv = 1.0f / sums[q];
            u16* op = attno + ((size_t)wi * 49 + q) * 256 + h * 32;
#pragma unroll
            for (int ci = 0; ci < 2; ++ci) {
                ushort4 d4;
                d4.x = f2b(o[ci][qj][0] * inv);
                d4.y = f2b(o[ci][qj][1] * inv);
                d4.z = f2b(o[ci][qj][2] * inv);
                d4.w = f2b(o[ci][qj][3] * inv);
                *(ushort4*)(op + 16 * ci + qd * 4) = d4;
            }
        }
    }
}

// window reverse + roll(+3,+3) + residual + LN2. One wave per natural token (chunk-local).
__global__ __launch_bounds__(256) void scatter_ln2_kernel(
    const float* __restrict__ x, size_t tok0, const u16* __restrict__ projo,
    const float* __restrict__ sc, const float* __restrict__ bi,
    u16* __restrict__ x2, u16* __restrict__ ln2o) {
    int tk = blockIdx.x * 4 + (threadIdx.x >> 6);
    int lane = threadIdx.x & 63;
    int b = tk / 3136, l = tk - b * 3136;
    int r = l / 56, c = l - r * 56;
    int r2 = r + 53; if (r2 >= 56) r2 -= 56;
    int c2 = c + 53; if (c2 >= 56) c2 -= 56;
    int wr = r2 / 7, ri = r2 - wr * 7;
    int wc = c2 / 7, ci = c2 - wc * 7;
    size_t t = ((size_t)(b * 64 + wr * 8 + wc)) * 49 + ri * 7 + ci;
    size_t loff = (size_t)tk * 256 + lane * 4;
    size_t goff = (tok0 + tk) * 256 + lane * 4;
    float4 xd = *(const float4*)(x + goff);
    ushort4 pd = *(const ushort4*)(projo + t * 256 + lane * 4);
    float v0 = xd.x + b2f(pd.x);
    float v1 = xd.y + b2f(pd.y);
    float v2 = xd.z + b2f(pd.z);
    float v3 = xd.w + b2f(pd.w);
    ushort4 o4;
    o4.x = f2b(v0); o4.y = f2b(v1); o4.z = f2b(v2); o4.w = f2b(v3);
    *(ushort4*)(x2 + loff) = o4;
    float s = v0 + v1 + v2 + v3;
    float ss = v0 * v0 + v1 * v1 + v2 * v2 + v3 * v3;
#pragma unroll
    for (int o = 32; o; o >>= 1) { s += __shfl_xor(s, o, 64); ss += __shfl_xor(ss, o, 64); }
    float mu = s * (1.0f / 256.0f);
    float rs = rsqrtf(ss * (1.0f / 256.0f) - mu * mu + 1e-6f);
    float4 s4 = *(const float4*)(sc + lane * 4);
    float4 b4 = *(const float4*)(bi + lane * 4);
    ushort4 n4;
    n4.x = f2b((v0 - mu) * rs * s4.x + b4.x);
    n4.y = f2b((v1 - mu) * rs * s4.y + b4.y);
    n4.z = f2b((v2 - mu) * rs * s4.z + b4.z);
    n4.w = f2b((v3 - mu) * rs * s4.w + b4.w);
    *(ushort4*)(ln2o + loff) = n4;
}

extern "C" void kernel_launch(void* const* d_in, const int* in_sizes, int n_in,
                              void* d_out, int out_size, void* d_ws, size_t ws_size,
                              hipStream_t stream) {
    const float* x     = (const float*)d_in[0];
    const float* ln1s  = (const float*)d_in[1];
    const float* ln1b  = (const float*)d_in[2];
    const float* qkvw  = (const float*)d_in[3];
    const float* qkvb  = (const float*)d_in[4];
    const float* projw = (const float*)d_in[5];
    const float* projb = (const float*)d_in[6];
    const float* btab  = (const float*)d_in[7];
    const float* ln2s  = (const float*)d_in[8];
    const float* ln2b  = (const float*)d_in[9];
    const float* fc1w  = (const float*)d_in[10];
    const float* fc1b  = (const float*)d_in[11];
    const float* fc2w  = (const float*)d_in[12];
    const float* fc2b  = (const float*)d_in[13];
    float* out = (float*)d_out;                 // FINAL OUTPUT IS FP32
    char* ws = (char*)d_ws;

    // ws: transposed bf16 weights (1.5 MB) + Sadd table (256 KB), then chunk regions.
    u16* wt_qkv  = (u16*)(ws + 0);        // 256x768^T   393216 B
    u16* wt_proj = (u16*)(ws + 393216);   // 256x256^T   131072 B
    u16* wt_fc1  = (u16*)(ws + 524288);   // 256x1024^T  524288 B
    u16* wt_fc2  = (u16*)(ws + 1048576);  // 1024x256^T  524288 B
    u16* saddt   = (u16*)(ws + 1572864);  // [4][8][64][64] bf16 = 262144 B
    const size_t base = 1835008;

    build_sadd<<<512, 256, 0, stream>>>(btab, saddt);
    transpose_k<<<768, 256, 0, stream>>>(qkvw, wt_qkv, 256, 768);
    transpose_k<<<256, 256, 0, stream>>>(projw, wt_proj, 256, 256);
    transpose_k<<<1024, 256, 0, stream>>>(fc1w, wt_fc1, 256, 1024);
    transpose_k<<<1024, 256, 0, stream>>>(fc2w, wt_fc2, 1024, 256);

    int NB = 16;
    while (NB > 1 && base + (size_t)NB * 3136 * 3072 > ws_size) NB >>= 1;
    const size_t T = (size_t)NB * 3136;

    u16* regA = (u16*)(ws + base);                       // T*512  B: win -> attno -> ln2o
    u16* regB = (u16*)(ws + base + T * 512);             // T*2048 B: qkv -> projo -> mlph
    u16* regX = (u16*)(ws + base + T * 512 + T * 2048);  // T*512  B: x2 residual

    for (int c0 = 0; c0 < 32; c0 += NB) {
        size_t tok0 = (size_t)c0 * 3136;
        float* outc = out + tok0 * 256;
        int Mc = (int)T;
        int gx = (Mc + 127) / 128;

        ln1_win_kernel<<<Mc / 4, 256, 0, stream>>>(x, tok0, ln1s, ln1b, regA);
        gemm_bt<0><<<dim3(6, gx), 256, 0, stream>>>(regA, wt_qkv, qkvb, nullptr,
                                                    regB, Mc, 768, 256);
        attn_kernel<<<NB * 128, 256, 0, stream>>>(regB, saddt, regA);
        gemm_bt<0><<<dim3(2, gx), 256, 0, stream>>>(regA, wt_proj, projb, nullptr,
                                                    regB, Mc, 256, 256);
        scatter_ln2_kernel<<<Mc / 4, 256, 0, stream>>>(x, tok0, regB, ln2s, ln2b,
                                                       regX, regA);
        gemm_bt<1><<<dim3(8, gx), 256, 0, stream>>>(regA, wt_fc1, fc1b, nullptr,
                                                    regB, Mc, 1024, 256);
        gemm_bt<2><<<dim3(2, gx), 256, 0, stream>>>(regB, wt_fc2, fc2b, regX,
                                                    outc, Mc, 256, 1024);
    }
}

// Round 4
// 761.768 us; speedup vs baseline: 1.4516x; 1.0532x over previous
//
#include <hip/hip_runtime.h>

typedef unsigned short u16;
typedef short short8v __attribute__((ext_vector_type(8)));
typedef float float4v __attribute__((ext_vector_type(4)));

__device__ __forceinline__ float b2f(u16 u) { return __uint_as_float(((unsigned)u) << 16); }
__device__ __forceinline__ u16 f2b(float f) {
    unsigned i = __float_as_uint(f);
    unsigned r = i + 0x7fffu + ((i >> 16) & 1u);
    return (u16)(r >> 16);
}
// tanh-gelu via hardware exp: 0.5x(1+tanh z) = x * (1 - 1/(e^{2z}+1)), exact identity.
__device__ __forceinline__ float gelu_f(float x) {
    float z2 = 1.5957691216057308f * (x + 0.044715f * x * x * x);  // 2*sqrt(2/pi)*(...)
    float e = __expf(z2);
    return x * (1.0f - 1.0f / (e + 1.0f));
}

typedef const __attribute__((address_space(1))) unsigned int* gas_ptr;
typedef __attribute__((address_space(3))) unsigned int* las_ptr;
// async global->LDS, 16B per lane, dest = wave-uniform base + lane*16
__device__ __forceinline__ void gload16(const u16* g, u16* l) {
    __builtin_amdgcn_global_load_lds((gas_ptr)g, (las_ptr)l, 16, 0, 0);
}

// out[n*K + k] = bf16(in[k*N + n])   (fp32 weights -> bf16 transposed, k-contiguous)
__global__ void transpose_k(const float* __restrict__ in, u16* __restrict__ out, int K, int N) {
    int idx = blockIdx.x * 256 + threadIdx.x;
    if (idx < K * N) {
        int n = idx / K;
        int k = idx - n * K;
        out[idx] = f2b(in[(size_t)k * N + n]);
    }
}

// Precompute Sadd[type][h][64][64] bf16: rel-pos bias + shift mask + key padding.
// type bit1 = (window row == 7), bit0 = (window col == 7). Keys>=49 => -1e30.
__global__ void build_sadd(const float* __restrict__ btab, u16* __restrict__ tbl) {
    int idx = blockIdx.x * 256 + threadIdx.x;  // 4*8*64*64 = 131072
    int key = idx & 63;
    int q = (idx >> 6) & 63;
    int h = (idx >> 12) & 7;
    int type = idx >> 15;
    float v;
    if (key >= 49 || q >= 49) {
        v = -1e30f;
    } else {
        int qy = q / 7, qx = q - qy * 7;      // query token coords
        int ky = key / 7, kx = key - ky * 7;  // key token coords
        int ridx = (qx - kx + 6) * 13 + (qy - ky + 6);
        v = btab[ridx * 8 + h];
        int rcq = (type & 2) ? (qy < 4 ? 1 : 2) : 0;
        int ccq = (type & 1) ? (qx < 4 ? 1 : 2) : 0;
        int rck = (type & 2) ? (ky < 4 ? 1 : 2) : 0;
        int cck = (type & 1) ? (kx < 4 ? 1 : 2) : 0;
        if (rcq * 3 + ccq != rck * 3 + cck) v += -100.0f;
    }
    tbl[idx] = f2b(v);
}

// LN1 + cyclic shift(-3,-3) + window partition. One wave per windowed token (chunk-local).
__global__ __launch_bounds__(256) void ln1_win_kernel(
    const float* __restrict__ x, size_t tok0, const float* __restrict__ sc,
    const float* __restrict__ bi, u16* __restrict__ win) {
    int t = blockIdx.x * 4 + (threadIdx.x >> 6);
    int lane = threadIdx.x & 63;
    int wi = t / 49, p = t - wi * 49;
    int b = wi >> 6, w = wi & 63;
    int wr = w >> 3, wc = w & 7;
    int ii = p / 7, jj = p - ii * 7;
    int r = wr * 7 + ii + 3; if (r >= 56) r -= 56;
    int c = wc * 7 + jj + 3; if (c >= 56) c -= 56;
    size_t off = (tok0 + (size_t)(b * 3136 + r * 56 + c)) * 256 + lane * 4;
    float4 d = *(const float4*)(x + off);
    float v0 = d.x, v1 = d.y, v2 = d.z, v3 = d.w;
    float s = v0 + v1 + v2 + v3;
    float ss = v0 * v0 + v1 * v1 + v2 * v2 + v3 * v3;
#pragma unroll
    for (int o = 32; o; o >>= 1) { s += __shfl_xor(s, o, 64); ss += __shfl_xor(ss, o, 64); }
    float mu = s * (1.0f / 256.0f);
    float rs = rsqrtf(ss * (1.0f / 256.0f) - mu * mu + 1e-6f);
    float4 s4 = *(const float4*)(sc + lane * 4);
    float4 b4 = *(const float4*)(bi + lane * 4);
    ushort4 o4;
    o4.x = f2b((v0 - mu) * rs * s4.x + b4.x);
    o4.y = f2b((v1 - mu) * rs * s4.y + b4.y);
    o4.z = f2b((v2 - mu) * rs * s4.z + b4.z);
    o4.w = f2b((v3 - mu) * rs * s4.w + b4.w);
    *(ushort4*)(win + (size_t)t * 256 + lane * 4) = o4;
}

// C[M,N] = A[M,K] @ Bt[N,K]^T + bias(fp32), M-guarded. A/Bt bf16.
// EPI: 0 = bias (bf16 out), 1 = bias+gelu (bf16 out), 2 = bias+residual (FP32 out).
// Grid: blockIdx.x = n-tile (fast, shares A-panel), blockIdx.y = m-tile.
// 2-phase double-buffered K-loop (T3 minimum recipe): STAGE(kt+1) issued before
// compute(kt); vmcnt(0) drained only AFTER compute (raw s_barrier, not
// __syncthreads, which would re-drain the fresh prefetch). Load latency hides
// under the current tile's ds_read+MFMA.
template <int EPI>
__global__ __launch_bounds__(256) void gemm_bt(
    const u16* __restrict__ A, const u16* __restrict__ Bt, const float* __restrict__ bias,
    const u16* __restrict__ res, void* __restrict__ Cout, int M, int N, int K) {
    // [buf][As 8192 u16 | Bs 8192 u16] = 64 KB; epilogue reuses flat [128][136] u16.
    __shared__ __align__(16) u16 smem[2][16384];
    int tid = threadIdx.x;
    int m0 = blockIdx.y * 128, n0 = blockIdx.x * 128;
    int lane = tid & 63, wave = tid >> 6;
    int wm = (wave >> 1) * 64, wn = (wave & 1) * 64;
    int lrow = lane & 15, qd = lane >> 4;
    int c0 = wave << 2;
    int rsub0 = lane >> 3;
    int kc = (((lane & 7) ^ rsub0) << 3);    // swizzled source slot
    float4v acc[4][4] = {};
    int kTiles = K >> 6;

    const u16* Aps[4];
    const u16* Bps[4];
#pragma unroll
    for (int i = 0; i < 4; ++i) {
        int c = c0 + i;
        int rsub = (c << 3) + rsub0;
        int rA = m0 + rsub; if (rA >= M) rA = M - 1;  // clamp; store is guarded
        Aps[i] = A + (size_t)rA * K + kc;
        Bps[i] = Bt + (size_t)(n0 + rsub) * K + kc;
    }
    // prologue: stage tile 0 into buf 0
#pragma unroll
    for (int i = 0; i < 4; ++i) {
        gload16(Aps[i], &smem[0][(c0 + i) << 9]);
        gload16(Bps[i], &smem[0][8192 + ((c0 + i) << 9)]);
    }
    asm volatile("s_waitcnt vmcnt(0)" ::: "memory");
    __builtin_amdgcn_s_barrier();

    for (int kt = 0; kt < kTiles; ++kt) {
        int cur = kt & 1;
        if (kt + 1 < kTiles) {
            int k0 = (kt + 1) << 6;
#pragma unroll
            for (int i = 0; i < 4; ++i) {
                gload16(Aps[i] + k0, &smem[cur ^ 1][(c0 + i) << 9]);
                gload16(Bps[i] + k0, &smem[cur ^ 1][8192 + ((c0 + i) << 9)]);
            }
        }
        const u16* As = smem[cur];
        const u16* Bs = smem[cur] + 8192;
#pragma unroll
        for (int ks = 0; ks < 64; ks += 32) {
            short8v af[4], bfr[4];
#pragma unroll
            for (int mi = 0; mi < 4; ++mi) {
                int row = wm + mi * 16 + lrow;
                int s = ((ks >> 3) + qd) ^ (row & 7);          // read-side XOR
                af[mi] = *(const short8v*)&As[row * 64 + (s << 3)];
            }
#pragma unroll
            for (int ni = 0; ni < 4; ++ni) {
                int row = wn + ni * 16 + lrow;
                int s = ((ks >> 3) + qd) ^ (row & 7);
                bfr[ni] = *(const short8v*)&Bs[row * 64 + (s << 3)];
            }
#pragma unroll
            for (int mi = 0; mi < 4; ++mi)
#pragma unroll
                for (int ni = 0; ni < 4; ++ni)
                    acc[mi][ni] = __builtin_amdgcn_mfma_f32_16x16x32_bf16(
                        af[mi], bfr[ni], acc[mi][ni], 0, 0, 0);
        }
        // drain the prefetch issued THIS iteration, then release the buffers.
        asm volatile("s_waitcnt vmcnt(0)" ::: "memory");
        __builtin_amdgcn_s_barrier();
    }
    if (EPI == 2) {
        // fp32 + residual scatter: 16 lanes x 4B = 64B row segments, txn-clean already.
#pragma unroll
        for (int ni = 0; ni < 4; ++ni) {
            int col = n0 + wn + ni * 16 + lrow;
            float bv = bias[col];
#pragma unroll
            for (int mi = 0; mi < 4; ++mi) {
#pragma unroll
                for (int rr = 0; rr < 4; ++rr) {
                    int row = m0 + wm + mi * 16 + qd * 4 + rr;
                    if (row < M) {
                        float v = acc[mi][ni][rr] + bv + b2f(res[(size_t)row * N + col]);
                        ((float*)Cout)[(size_t)row * N + col] = v;
                    }
                }
            }
        }
    } else {
        // bf16 out: transpose-stage via LDS (row stride 136 u16 = 272B: 16B-aligned,
        // write conflicts 2-way=free), then 16B coalesced stores.
        u16* ep = (u16*)smem;
#pragma unroll
        for (int ni = 0; ni < 4; ++ni) {
            float bv = bias[n0 + wn + ni * 16 + lrow];
#pragma unroll
            for (int mi = 0; mi < 4; ++mi) {
#pragma unroll
                for (int rr = 0; rr < 4; ++rr) {
                    float v = acc[mi][ni][rr] + bv;
                    if (EPI == 1) v = gelu_f(v);
                    ep[(wm + mi * 16 + qd * 4 + rr) * 136 + wn + ni * 16 + lrow] = f2b(v);
                }
            }
        }
        __syncthreads();
        u16* outp = (u16*)Cout;
#pragma unroll
        for (int j = 0; j < 8; ++j) {
            int slot = j * 256 + tid;
            int row = slot >> 4, cs = (slot & 15) << 3;
            short8v vv = *(const short8v*)&ep[row * 136 + cs];
            int grow = m0 + row;
            if (grow < M)
                *(short8v*)(outp + (size_t)grow * N + n0 + cs) = vv;
        }
    }
}

// MFMA attention. One wave per (window, head); barrier-free (wave-private LDS).
// S = Q K^T via 16 mfma_16x16x32 (d=32 = one K-step); softmax in C-layout;
// P (bf16, unnormalized) + V^T staged in swizzled LDS; O^T = V^T P^T via 16 mfma;
// 1/rowsum applied at the output.
__global__ __launch_bounds__(256) void attn_kernel(
    const u16* __restrict__ qkv, const u16* __restrict__ sadd, u16* __restrict__ attno) {
    // per wave: P[64][64] u16 swz (8192B) | Vt[32][64] u16 swz (4096B) | sums[64] f32 (256B)
    __shared__ __align__(16) u16 lds[4][6272];  // 50176 B total
    int wave = threadIdx.x >> 6, lane = threadIdx.x & 63;
    u16* Plds = lds[wave];
    u16* Vt = lds[wave] + 4096;
    float* sums = (float*)(lds[wave] + 6144);
    int u = blockIdx.x * 4 + wave;
    int wi = u >> 3, h = u & 7;
    int w = wi & 63;
    int type = (((w >> 3) == 7) ? 2 : 0) | (((w & 7) == 7) ? 1 : 0);
    const u16* base = qkv + (size_t)wi * 49 * 768 + h * 32;
    int lrow = lane & 15, qd = lane >> 4;

    // zero Vt (padded tokens 49..63 must not contain NaN bits), then stage V^T swizzled.
#pragma unroll
    for (int z = 0; z < 4; ++z)
        *(short8v*)&Vt[(z * 64 + lane) * 8] = (short8v){0, 0, 0, 0, 0, 0, 0, 0};
    for (int idx = lane; idx < 196; idx += 64) {
        int t = idx >> 2, part = (idx & 3) << 3;
        uint4 vd = *(const uint4*)(base + 512 + (size_t)t * 768 + part);
        const u16* vs = (const u16*)&vd;
#pragma unroll
        for (int e = 0; e < 8; ++e) {
            int c = part + e;
            Vt[c * 64 + ((((t >> 3) ^ (c & 7)) << 3) | (t & 7))] = vs[e];
        }
    }

    // Q,K fragments straight from global (token-major == fragment layout).
    short8v qf[4], kf[4];
#pragma unroll
    for (int i = 0; i < 4; ++i) {
        qf[i] = *(const short8v*)(base + (size_t)(16 * i + lrow) * 768 + qd * 8);
        kf[i] = *(const short8v*)(base + 256 + (size_t)(16 * i + lrow) * 768 + qd * 8);
    }
    float4v s[4][4];
#pragma unroll
    for (int i = 0; i < 4; ++i)
#pragma unroll
        for (int j = 0; j < 4; ++j)
            s[i][j] = __builtin_amdgcn_mfma_f32_16x16x32_bf16(
                qf[i], kf[j], (float4v){0.f, 0.f, 0.f, 0.f}, 0, 0, 0);

    // scale + bias/mask table; padded-key tile overwritten (kills inf/NaN).
    const float scale = 0.17677669529663687f;  // 32^-0.5
    const u16* tb = sadd + ((size_t)(type * 8 + h) << 12);
#pragma unroll
    for (int i = 0; i < 4; ++i)
#pragma unroll
        for (int j = 0; j < 4; ++j)
#pragma unroll
            for (int rr = 0; rr < 4; ++rr) {
                int q = 16 * i + qd * 4 + rr, key = 16 * j + lrow;
                float v = s[i][j][rr] * scale + b2f(tb[q * 64 + key]);
                if (j == 3 && lrow > 0) v = -1e30f;
                s[i][j][rr] = v;
            }
    // row max (over j-tiles, then 16-lane column group)
    float rmx[4][4];
#pragma unroll
    for (int i = 0; i < 4; ++i)
#pragma unroll
        for (int rr = 0; rr < 4; ++rr) {
            float m = fmaxf(fmaxf(s[i][0][rr], s[i][1][rr]), fmaxf(s[i][2][rr], s[i][3][rr]));
#pragma unroll
            for (int o = 1; o < 16; o <<= 1) m = fmaxf(m, __shfl_xor(m, o, 64));
            rmx[i][rr] = m;
        }
    // exp, row sum, write P (bf16, unnormalized) swizzled
    int hi = lrow >> 3, lo = lrow & 7;
#pragma unroll
    for (int i = 0; i < 4; ++i)
#pragma unroll
        for (int rr = 0; rr < 4; ++rr) {
            int q = 16 * i + qd * 4 + rr;
            float e0 = __expf(s[i][0][rr] - rmx[i][rr]);
            float e1 = __expf(s[i][1][rr] - rmx[i][rr]);
            float e2 = __expf(s[i][2][rr] - rmx[i][rr]);
            float e3 = __expf(s[i][3][rr] - rmx[i][rr]);
            float sm = (e0 + e1) + (e2 + e3);
#pragma unroll
            for (int o = 1; o < 16; o <<= 1) sm += __shfl_xor(sm, o, 64);
            int q64 = q * 64, q7 = q & 7;
            Plds[q64 + ((((0 + hi) ^ q7) << 3) | lo)] = f2b(e0);
            Plds[q64 + ((((2 + hi) ^ q7) << 3) | lo)] = f2b(e1);
            Plds[q64 + ((((4 + hi) ^ q7) << 3) | lo)] = f2b(e2);
            Plds[q64 + ((((6 + hi) ^ q7) << 3) | lo)] = f2b(e3);
            if (lrow == 0) sums[q] = sm;
        }

    // O^T = V^T @ P^T : A-frag = Vt rows (channels), B-frag = P rows (queries as cols).
    float4v o[2][4] = {};
#pragma unroll
    for (int ks = 0; ks < 2; ++ks) {
        short8v av[2], bp[4];
#pragma unroll
        for (int ci = 0; ci < 2; ++ci) {
            int c = 16 * ci + lrow;
            av[ci] = *(const short8v*)&Vt[c * 64 + ((((ks << 2) + qd) ^ (c & 7)) << 3)];
        }
#pragma unroll
        for (int qj = 0; qj < 4; ++qj) {
            int q = 16 * qj + lrow;
            bp[qj] = *(const short8v*)&Plds[q * 64 + ((((ks << 2) + qd) ^ (q & 7)) << 3)];
        }
#pragma unroll
        for (int ci = 0; ci < 2; ++ci)
#pragma unroll
            for (int qj = 0; qj < 4; ++qj)
                o[ci][qj] = __builtin_amdgcn_mfma_f32_16x16x32_bf16(
                    av[ci], bp[qj], o[ci][qj], 0, 0, 0);
    }
    // normalize rows by 1/sum and store: O^T[c][q] -> attno[token q][h*32 + c]
#pragma unroll
    for (int qj = 0; qj < 4; ++qj) {
        int q = 16 * qj + lrow;
        if (q < 49) {
            float inv = 1.0f / sums[q];
            u16* op = attno + ((size_t)wi * 49 + q) * 256 + h * 32;
#pragma unroll
            for (int ci = 0; ci < 2; ++ci) {
                ushort4 d4;
                d4.x = f2b(o[ci][qj][0] * inv);
                d4.y = f2b(o[ci][qj][1] * inv);
                d4.z = f2b(o[ci][qj][2] * inv);
                d4.w = f2b(o[ci][qj][3] * inv);
                *(ushort4*)(op + 16 * ci + qd * 4) = d4;
            }
        }
    }
}

// window reverse + roll(+3,+3) + residual + LN2. One wave per natural token (chunk-local).
__global__ __launch_bounds__(256) void scatter_ln2_kernel(
    const float* __restrict__ x, size_t tok0, const u16* __restrict__ projo,
    const float* __restrict__ sc, const float* __restrict__ bi,
    u16* __restrict__ x2, u16* __restrict__ ln2o) {
    int tk = blockIdx.x * 4 + (threadIdx.x >> 6);
    int lane = threadIdx.x & 63;
    int b = tk / 3136, l = tk - b * 3136;
    int r = l / 56, c = l - r * 56;
    int r2 = r + 53; if (r2 >= 56) r2 -= 56;
    int c2 = c + 53; if (c2 >= 56) c2 -= 56;
    int wr = r2 / 7, ri = r2 - wr * 7;
    int wc = c2 / 7, ci = c2 - wc * 7;
    size_t t = ((size_t)(b * 64 + wr * 8 + wc)) * 49 + ri * 7 + ci;
    size_t loff = (size_t)tk * 256 + lane * 4;
    size_t goff = (tok0 + tk) * 256 + lane * 4;
    float4 xd = *(const float4*)(x + goff);
    ushort4 pd = *(const ushort4*)(projo + t * 256 + lane * 4);
    float v0 = xd.x + b2f(pd.x);
    float v1 = xd.y + b2f(pd.y);
    float v2 = xd.z + b2f(pd.z);
    float v3 = xd.w + b2f(pd.w);
    ushort4 o4;
    o4.x = f2b(v0); o4.y = f2b(v1); o4.z = f2b(v2); o4.w = f2b(v3);
    *(ushort4*)(x2 + loff) = o4;
    float s = v0 + v1 + v2 + v3;
    float ss = v0 * v0 + v1 * v1 + v2 * v2 + v3 * v3;
#pragma unroll
    for (int o = 32; o; o >>= 1) { s += __shfl_xor(s, o, 64); ss += __shfl_xor(ss, o, 64); }
    float mu = s * (1.0f / 256.0f);
    float rs = rsqrtf(ss * (1.0f / 256.0f) - mu * mu + 1e-6f);
    float4 s4 = *(const float4*)(sc + lane * 4);
    float4 b4 = *(const float4*)(bi + lane * 4);
    ushort4 n4;
    n4.x = f2b((v0 - mu) * rs * s4.x + b4.x);
    n4.y = f2b((v1 - mu) * rs * s4.y + b4.y);
    n4.z = f2b((v2 - mu) * rs * s4.z + b4.z);
    n4.w = f2b((v3 - mu) * rs * s4.w + b4.w);
    *(ushort4*)(ln2o + loff) = n4;
}

extern "C" void kernel_launch(void* const* d_in, const int* in_sizes, int n_in,
                              void* d_out, int out_size, void* d_ws, size_t ws_size,
                              hipStream_t stream) {
    const float* x     = (const float*)d_in[0];
    const float* ln1s  = (const float*)d_in[1];
    const float* ln1b  = (const float*)d_in[2];
    const float* qkvw  = (const float*)d_in[3];
    const float* qkvb  = (const float*)d_in[4];
    const float* projw = (const float*)d_in[5];
    const float* projb = (const float*)d_in[6];
    const float* btab  = (const float*)d_in[7];
    const float* ln2s  = (const float*)d_in[8];
    const float* ln2b  = (const float*)d_in[9];
    const float* fc1w  = (const float*)d_in[10];
    const float* fc1b  = (const float*)d_in[11];
    const float* fc2w  = (const float*)d_in[12];
    const float* fc2b  = (const float*)d_in[13];
    float* out = (float*)d_out;                 // FINAL OUTPUT IS FP32
    char* ws = (char*)d_ws;

    // ws: transposed bf16 weights (1.5 MB) + Sadd table (256 KB), then chunk regions.
    u16* wt_qkv  = (u16*)(ws + 0);        // 256x768^T   393216 B
    u16* wt_proj = (u16*)(ws + 393216);   // 256x256^T   131072 B
    u16* wt_fc1  = (u16*)(ws + 524288);   // 256x1024^T  524288 B
    u16* wt_fc2  = (u16*)(ws + 1048576);  // 1024x256^T  524288 B
    u16* saddt   = (u16*)(ws + 1572864);  // [4][8][64][64] bf16 = 262144 B
    const size_t base = 1835008;

    build_sadd<<<512, 256, 0, stream>>>(btab, saddt);
    transpose_k<<<768, 256, 0, stream>>>(qkvw, wt_qkv, 256, 768);
    transpose_k<<<256, 256, 0, stream>>>(projw, wt_proj, 256, 256);
    transpose_k<<<1024, 256, 0, stream>>>(fc1w, wt_fc1, 256, 1024);
    transpose_k<<<1024, 256, 0, stream>>>(fc2w, wt_fc2, 1024, 256);

    int NB = 16;
    while (NB > 1 && base + (size_t)NB * 3136 * 3072 > ws_size) NB >>= 1;
    const size_t T = (size_t)NB * 3136;

    u16* regA = (u16*)(ws + base);                       // T*512  B: win -> attno -> ln2o
    u16* regB = (u16*)(ws + base + T * 512);             // T*2048 B: qkv -> projo -> mlph
    u16* regX = (u16*)(ws + base + T * 512 + T * 2048);  // T*512  B: x2 residual

    for (int c0 = 0; c0 < 32; c0 += NB) {
        size_t tok0 = (size_t)c0 * 3136;
        float* outc = out + tok0 * 256;
        int Mc = (int)T;
        int gx = (Mc + 127) / 128;

        ln1_win_kernel<<<Mc / 4, 256, 0, stream>>>(x, tok0, ln1s, ln1b, regA);
        gemm_bt<0><<<dim3(6, gx), 256, 0, stream>>>(regA, wt_qkv, qkvb, nullptr,
                                                    regB, Mc, 768, 256);
        attn_kernel<<<NB * 128, 256, 0, stream>>>(regB, saddt, regA);
        gemm_bt<0><<<dim3(2, gx), 256, 0, stream>>>(regA, wt_proj, projb, nullptr,
                                                    regB, Mc, 256, 256);
        scatter_ln2_kernel<<<Mc / 4, 256, 0, stream>>>(x, tok0, regB, ln2s, ln2b,
                                                       regX, regA);
        gemm_bt<1><<<dim3(8, gx), 256, 0, stream>>>(regA, wt_fc1, fc1b, nullptr,
                                                    regB, Mc, 1024, 256);
        gemm_bt<2><<<dim3(2, gx), 256, 0, stream>>>(regB, wt_fc2, fc2b, regX,
                                                    outc, Mc, 256, 1024);
    }
}

// Round 5
// 704.235 us; speedup vs baseline: 1.5702x; 1.0817x over previous
//
#include <hip/hip_runtime.h>

typedef unsigned short u16;
typedef short short8v __attribute__((ext_vector_type(8)));
typedef float float4v __attribute__((ext_vector_type(4)));

__device__ __forceinline__ float b2f(u16 u) { return __uint_as_float(((unsigned)u) << 16); }
__device__ __forceinline__ u16 f2b(float f) {
    unsigned i = __float_as_uint(f);
    unsigned r = i + 0x7fffu + ((i >> 16) & 1u);
    return (u16)(r >> 16);
}
// tanh-gelu via hardware exp + fast rcp (1-ulp; noise vs bf16 rounding).
// 0.5x(1+tanh z) = x - x/(e^{2z}+1), exact identity.
__device__ __forceinline__ float gelu_f(float x) {
    float t = x * x;
    float z2 = 1.5957691216057308f * x * __builtin_fmaf(0.044715f, t, 1.0f);
    float e = __expf(z2);
    return x - x * __builtin_amdgcn_rcpf(e + 1.0f);
}

typedef const __attribute__((address_space(1))) unsigned int* gas_ptr;
typedef __attribute__((address_space(3))) unsigned int* las_ptr;
// async global->LDS, 16B per lane, dest = wave-uniform base + lane*16
__device__ __forceinline__ void gload16(const u16* g, u16* l) {
    __builtin_amdgcn_global_load_lds((gas_ptr)g, (las_ptr)l, 16, 0, 0);
}

// out[n*K + k] = bf16(in[k*N + n])   (fp32 weights -> bf16 transposed, k-contiguous)
__global__ void transpose_k(const float* __restrict__ in, u16* __restrict__ out, int K, int N) {
    int idx = blockIdx.x * 256 + threadIdx.x;
    if (idx < K * N) {
        int n = idx / K;
        int k = idx - n * K;
        out[idx] = f2b(in[(size_t)k * N + n]);
    }
}

// Precompute Sadd[type][h][64][64] bf16: rel-pos bias + shift mask + key padding.
// type bit1 = (window row == 7), bit0 = (window col == 7). Keys>=49 => -1e30.
__global__ void build_sadd(const float* __restrict__ btab, u16* __restrict__ tbl) {
    int idx = blockIdx.x * 256 + threadIdx.x;  // 4*8*64*64 = 131072
    int key = idx & 63;
    int q = (idx >> 6) & 63;
    int h = (idx >> 12) & 7;
    int type = idx >> 15;
    float v;
    if (key >= 49 || q >= 49) {
        v = -1e30f;
    } else {
        int qy = q / 7, qx = q - qy * 7;      // query token coords
        int ky = key / 7, kx = key - ky * 7;  // key token coords
        int ridx = (qx - kx + 6) * 13 + (qy - ky + 6);
        v = btab[ridx * 8 + h];
        int rcq = (type & 2) ? (qy < 4 ? 1 : 2) : 0;
        int ccq = (type & 1) ? (qx < 4 ? 1 : 2) : 0;
        int rck = (type & 2) ? (ky < 4 ? 1 : 2) : 0;
        int cck = (type & 1) ? (kx < 4 ? 1 : 2) : 0;
        if (rcq * 3 + ccq != rck * 3 + cck) v += -100.0f;
    }
    tbl[idx] = f2b(v);
}

// LN1 + cyclic shift(-3,-3) + window partition. One wave per windowed token (chunk-local).
__global__ __launch_bounds__(256) void ln1_win_kernel(
    const float* __restrict__ x, size_t tok0, const float* __restrict__ sc,
    const float* __restrict__ bi, u16* __restrict__ win) {
    int t = blockIdx.x * 4 + (threadIdx.x >> 6);
    int lane = threadIdx.x & 63;
    int wi = t / 49, p = t - wi * 49;
    int b = wi >> 6, w = wi & 63;
    int wr = w >> 3, wc = w & 7;
    int ii = p / 7, jj = p - ii * 7;
    int r = wr * 7 + ii + 3; if (r >= 56) r -= 56;
    int c = wc * 7 + jj + 3; if (c >= 56) c -= 56;
    size_t off = (tok0 + (size_t)(b * 3136 + r * 56 + c)) * 256 + lane * 4;
    float4 d = *(const float4*)(x + off);
    float v0 = d.x, v1 = d.y, v2 = d.z, v3 = d.w;
    float s = v0 + v1 + v2 + v3;
    float ss = v0 * v0 + v1 * v1 + v2 * v2 + v3 * v3;
#pragma unroll
    for (int o = 32; o; o >>= 1) { s += __shfl_xor(s, o, 64); ss += __shfl_xor(ss, o, 64); }
    float mu = s * (1.0f / 256.0f);
    float rs = rsqrtf(ss * (1.0f / 256.0f) - mu * mu + 1e-6f);
    float4 s4 = *(const float4*)(sc + lane * 4);
    float4 b4 = *(const float4*)(bi + lane * 4);
    ushort4 o4;
    o4.x = f2b((v0 - mu) * rs * s4.x + b4.x);
    o4.y = f2b((v1 - mu) * rs * s4.y + b4.y);
    o4.z = f2b((v2 - mu) * rs * s4.z + b4.z);
    o4.w = f2b((v3 - mu) * rs * s4.w + b4.w);
    *(ushort4*)(win + (size_t)t * 256 + lane * 4) = o4;
}

// C[M,N] = A[M,K] @ Bt[N,K]^T + bias(fp32), M-guarded. A/Bt bf16.
// EPI: 0 = bias (bf16 out), 1 = bias+gelu (bf16 out), 2 = bias+residual (FP32 out).
// XCD-aware remap: each XCD owns a contiguous slab of m-tiles, n innermost, so
// the 64KB A-panel is fetched into ONE XCD L2 (round-robin d%8 assumption; pure
// permutation either way). Requires gridDim.y % 8 == 0, else identity.
// 2-phase double-buffered K-loop (T3 minimum): STAGE(kt+1) before compute(kt),
// vmcnt(0) drained AFTER compute (raw s_barrier, not __syncthreads).
template <int EPI>
__global__ __launch_bounds__(256) void gemm_bt(
    const u16* __restrict__ A, const u16* __restrict__ Bt, const float* __restrict__ bias,
    const u16* __restrict__ res, void* __restrict__ Cout, int M, int N, int K) {
    // [buf][As 8192 u16 | Bs 8192 u16] = 64 KB; epilogue reuses flat [128][136] u16.
    __shared__ __align__(16) u16 smem[2][16384];
    int tid = threadIdx.x;
    int bidx = blockIdx.x, bidy = blockIdx.y;
    int nn = gridDim.x, nm = gridDim.y;
    if ((nm & 7) == 0) {
        int d = bidy * nn + bidx;
        int x = d & 7, j = d >> 3;
        int mloc = j / nn;
        bidx = j - mloc * nn;
        bidy = x * (nm >> 3) + mloc;
    }
    int m0 = bidy * 128, n0 = bidx * 128;
    int lane = tid & 63, wave = tid >> 6;
    int wm = (wave >> 1) * 64, wn = (wave & 1) * 64;
    int lrow = lane & 15, qd = lane >> 4;
    int c0 = wave << 2;
    int rsub0 = lane >> 3;
    int kc = (((lane & 7) ^ rsub0) << 3);    // swizzled source slot
    float4v acc[4][4] = {};
    int kTiles = K >> 6;

    const u16* Aps[4];
    const u16* Bps[4];
#pragma unroll
    for (int i = 0; i < 4; ++i) {
        int c = c0 + i;
        int rsub = (c << 3) + rsub0;
        int rA = m0 + rsub; if (rA >= M) rA = M - 1;  // clamp; store is guarded
        Aps[i] = A + (size_t)rA * K + kc;
        Bps[i] = Bt + (size_t)(n0 + rsub) * K + kc;
    }
    // prologue: stage tile 0 into buf 0
#pragma unroll
    for (int i = 0; i < 4; ++i) {
        gload16(Aps[i], &smem[0][(c0 + i) << 9]);
        gload16(Bps[i], &smem[0][8192 + ((c0 + i) << 9)]);
    }
    asm volatile("s_waitcnt vmcnt(0)" ::: "memory");
    __builtin_amdgcn_s_barrier();

    for (int kt = 0; kt < kTiles; ++kt) {
        int cur = kt & 1;
        if (kt + 1 < kTiles) {
            int k0 = (kt + 1) << 6;
#pragma unroll
            for (int i = 0; i < 4; ++i) {
                gload16(Aps[i] + k0, &smem[cur ^ 1][(c0 + i) << 9]);
                gload16(Bps[i] + k0, &smem[cur ^ 1][8192 + ((c0 + i) << 9)]);
            }
        }
        const u16* As = smem[cur];
        const u16* Bs = smem[cur] + 8192;
#pragma unroll
        for (int ks = 0; ks < 64; ks += 32) {
            short8v af[4], bfr[4];
#pragma unroll
            for (int mi = 0; mi < 4; ++mi) {
                int row = wm + mi * 16 + lrow;
                int s = ((ks >> 3) + qd) ^ (row & 7);          // read-side XOR
                af[mi] = *(const short8v*)&As[row * 64 + (s << 3)];
            }
#pragma unroll
            for (int ni = 0; ni < 4; ++ni) {
                int row = wn + ni * 16 + lrow;
                int s = ((ks >> 3) + qd) ^ (row & 7);
                bfr[ni] = *(const short8v*)&Bs[row * 64 + (s << 3)];
            }
#pragma unroll
            for (int mi = 0; mi < 4; ++mi)
#pragma unroll
                for (int ni = 0; ni < 4; ++ni)
                    acc[mi][ni] = __builtin_amdgcn_mfma_f32_16x16x32_bf16(
                        af[mi], bfr[ni], acc[mi][ni], 0, 0, 0);
        }
        // drain the prefetch issued THIS iteration, then release the buffers.
        asm volatile("s_waitcnt vmcnt(0)" ::: "memory");
        __builtin_amdgcn_s_barrier();
    }
    if (EPI == 2) {
        // fp32 + residual scatter: 16 lanes x 4B = 64B row segments, txn-clean already.
#pragma unroll
        for (int ni = 0; ni < 4; ++ni) {
            int col = n0 + wn + ni * 16 + lrow;
            float bv = bias[col];
#pragma unroll
            for (int mi = 0; mi < 4; ++mi) {
#pragma unroll
                for (int rr = 0; rr < 4; ++rr) {
                    int row = m0 + wm + mi * 16 + qd * 4 + rr;
                    if (row < M) {
                        float v = acc[mi][ni][rr] + bv + b2f(res[(size_t)row * N + col]);
                        ((float*)Cout)[(size_t)row * N + col] = v;
                    }
                }
            }
        }
    } else {
        // bf16 out: transpose-stage via LDS (row stride 136 u16 = 272B: 16B-aligned,
        // write conflicts 2-way=free), then 16B coalesced stores.
        u16* ep = (u16*)smem;
#pragma unroll
        for (int ni = 0; ni < 4; ++ni) {
            float bv = bias[n0 + wn + ni * 16 + lrow];
#pragma unroll
            for (int mi = 0; mi < 4; ++mi) {
#pragma unroll
                for (int rr = 0; rr < 4; ++rr) {
                    float v = acc[mi][ni][rr] + bv;
                    if (EPI == 1) v = gelu_f(v);
                    ep[(wm + mi * 16 + qd * 4 + rr) * 136 + wn + ni * 16 + lrow] = f2b(v);
                }
            }
        }
        __syncthreads();
        u16* outp = (u16*)Cout;
#pragma unroll
        for (int j = 0; j < 8; ++j) {
            int slot = j * 256 + tid;
            int row = slot >> 4, cs = (slot & 15) << 3;
            short8v vv = *(const short8v*)&ep[row * 136 + cs];
            int grow = m0 + row;
            if (grow < M)
                *(short8v*)(outp + (size_t)grow * N + n0 + cs) = vv;
        }
    }
}

// MFMA attention. One wave per (window, head); barrier-free (wave-private LDS).
// S = Q K^T via 16 mfma_16x16x32 (d=32 = one K-step); softmax in C-layout;
// P (bf16, unnormalized) + V^T staged in swizzled LDS; O^T = V^T P^T via 16 mfma;
// 1/rowsum applied at the output.
__global__ __launch_bounds__(256) void attn_kernel(
    const u16* __restrict__ qkv, const u16* __restrict__ sadd, u16* __restrict__ attno) {
    // per wave: P[64][64] u16 swz (8192B) | Vt[32][64] u16 swz (4096B) | sums[64] f32 (256B)
    __shared__ __align__(16) u16 lds[4][6272];  // 50176 B total
    int wave = threadIdx.x >> 6, lane = threadIdx.x & 63;
    u16* Plds = lds[wave];
    u16* Vt = lds[wave] + 4096;
    float* sums = (float*)(lds[wave] + 6144);
    int u = blockIdx.x * 4 + wave;
    int wi = u >> 3, h = u & 7;
    int w = wi & 63;
    int type = (((w >> 3) == 7) ? 2 : 0) | (((w & 7) == 7) ? 1 : 0);
    const u16* base = qkv + (size_t)wi * 49 * 768 + h * 32;
    int lrow = lane & 15, qd = lane >> 4;

    // zero Vt (padded tokens 49..63 must not contain NaN bits), then stage V^T swizzled.
#pragma unroll
    for (int z = 0; z < 4; ++z)
        *(short8v*)&Vt[(z * 64 + lane) * 8] = (short8v){0, 0, 0, 0, 0, 0, 0, 0};
    for (int idx = lane; idx < 196; idx += 64) {
        int t = idx >> 2, part = (idx & 3) << 3;
        uint4 vd = *(const uint4*)(base + 512 + (size_t)t * 768 + part);
        const u16* vs = (const u16*)&vd;
#pragma unroll
        for (int e = 0; e < 8; ++e) {
            int c = part + e;
            Vt[c * 64 + ((((t >> 3) ^ (c & 7)) << 3) | (t & 7))] = vs[e];
        }
    }

    // Q,K fragments straight from global (token-major == fragment layout).
    short8v qf[4], kf[4];
#pragma unroll
    for (int i = 0; i < 4; ++i) {
        qf[i] = *(const short8v*)(base + (size_t)(16 * i + lrow) * 768 + qd * 8);
        kf[i] = *(const short8v*)(base + 256 + (size_t)(16 * i + lrow) * 768 + qd * 8);
    }
    float4v s[4][4];
#pragma unroll
    for (int i = 0; i < 4; ++i)
#pragma unroll
        for (int j = 0; j < 4; ++j)
            s[i][j] = __builtin_amdgcn_mfma_f32_16x16x32_bf16(
                qf[i], kf[j], (float4v){0.f, 0.f, 0.f, 0.f}, 0, 0, 0);

    // scale + bias/mask table; padded-key tile overwritten (kills inf/NaN).
    const float scale = 0.17677669529663687f;  // 32^-0.5
    const u16* tb = sadd + ((size_t)(type * 8 + h) << 12);
#pragma unroll
    for (int i = 0; i < 4; ++i)
#pragma unroll
        for (int j = 0; j < 4; ++j)
#pragma unroll
            for (int rr = 0; rr < 4; ++rr) {
                int q = 16 * i + qd * 4 + rr, key = 16 * j + lrow;
                float v = s[i][j][rr] * scale + b2f(tb[q * 64 + key]);
                if (j == 3 && lrow > 0) v = -1e30f;
                s[i][j][rr] = v;
            }
    // row max (over j-tiles, then 16-lane column group)
    float rmx[4][4];
#pragma unroll
    for (int i = 0; i < 4; ++i)
#pragma unroll
        for (int rr = 0; rr < 4; ++rr) {
            float m = fmaxf(fmaxf(s[i][0][rr], s[i][1][rr]), fmaxf(s[i][2][rr], s[i][3][rr]));
#pragma unroll
            for (int o = 1; o < 16; o <<= 1) m = fmaxf(m, __shfl_xor(m, o, 64));
            rmx[i][rr] = m;
        }
    // exp, row sum, write P (bf16, unnormalized) swizzled
    int hi = lrow >> 3, lo = lrow & 7;
#pragma unroll
    for (int i = 0; i < 4; ++i)
#pragma unroll
        for (int rr = 0; rr < 4; ++rr) {
            int q = 16 * i + qd * 4 + rr;
            float e0 = __expf(s[i][0][rr] - rmx[i][rr]);
            float e1 = __expf(s[i][1][rr] - rmx[i][rr]);
            float e2 = __expf(s[i][2][rr] - rmx[i][rr]);
            float e3 = __expf(s[i][3][rr] - rmx[i][rr]);
            float sm = (e0 + e1) + (e2 + e3);
#pragma unroll
            for (int o = 1; o < 16; o <<= 1) sm += __shfl_xor(sm, o, 64);
            int q64 = q * 64, q7 = q & 7;
            Plds[q64 + ((((0 + hi) ^ q7) << 3) | lo)] = f2b(e0);
            Plds[q64 + ((((2 + hi) ^ q7) << 3) | lo)] = f2b(e1);
            Plds[q64 + ((((4 + hi) ^ q7) << 3) | lo)] = f2b(e2);
            Plds[q64 + ((((6 + hi) ^ q7) << 3) | lo)] = f2b(e3);
            if (lrow == 0) sums[q] = sm;
        }

    // O^T = V^T @ P^T : A-frag = Vt rows (channels), B-frag = P rows (queries as cols).
    float4v o[2][4] = {};
#pragma unroll
    for (int ks = 0; ks < 2; ++ks) {
        short8v av[2], bp[4];
#pragma unroll
        for (int ci = 0; ci < 2; ++ci) {
            int c = 16 * ci + lrow;
            av[ci] = *(const short8v*)&Vt[c * 64 + ((((ks << 2) + qd) ^ (c & 7)) << 3)];
        }
#pragma unroll
        for (int qj = 0; qj < 4; ++qj) {
            int q = 16 * qj + lrow;
            bp[qj] = *(const short8v*)&Plds[q * 64 + ((((ks << 2) + qd) ^ (q & 7)) << 3)];
        }
#pragma unroll
        for (int ci = 0; ci < 2; ++ci)
#pragma unroll
            for (int qj = 0; qj < 4; ++qj)
                o[ci][qj] = __builtin_amdgcn_mfma_f32_16x16x32_bf16(
                    av[ci], bp[qj], o[ci][qj], 0, 0, 0);
    }
    // normalize rows by 1/sum and store: O^T[c][q] -> attno[token q][h*32 + c]
#pragma unroll
    for (int qj = 0; qj < 4; ++qj) {
        int q = 16 * qj + lrow;
        if (q < 49) {
            float inv = __builtin_amdgcn_rcpf(sums[q]);
            u16* op = attno + ((size_t)wi * 49 + q) * 256 + h * 32;
#pragma unroll
            for (int ci = 0; ci < 2; ++ci) {
                ushort4 d4;
                d4.x = f2b(o[ci][qj][0] * inv);
                d4.y = f2b(o[ci][qj][1] * inv);
                d4.z = f2b(o[ci][qj][2] * inv);
                d4.w = f2b(o[ci][qj][3] * inv);
                *(ushort4*)(op + 16 * ci + qd * 4) = d4;
            }
        }
    }
}

// window reverse + roll(+3,+3) + residual + LN2. One wave per natural token (chunk-local).
__global__ __launch_bounds__(256) void scatter_ln2_kernel(
    const float* __restrict__ x, size_t tok0, const u16* __restrict__ projo,
    const float* __restrict__ sc, const float* __restrict__ bi,
    u16* __restrict__ x2, u16* __restrict__ ln2o) {
    int tk = blockIdx.x * 4 + (threadIdx.x >> 6);
    int lane = threadIdx.x & 63;
    int b = tk / 3136, l = tk - b * 3136;
    int r = l / 56, c = l - r * 56;
    int r2 = r + 53; if (r2 >= 56) r2 -= 56;
    int c2 = c + 53; if (c2 >= 56) c2 -= 56;
    int wr = r2 / 7, ri = r2 - wr * 7;
    int wc = c2 / 7, ci = c2 - wc * 7;
    size_t t = ((size_t)(b * 64 + wr * 8 + wc)) * 49 + ri * 7 + ci;
    size_t loff = (size_t)tk * 256 + lane * 4;
    size_t goff = (tok0 + tk) * 256 + lane * 4;
    float4 xd = *(const float4*)(x + goff);
    ushort4 pd = *(const ushort4*)(projo + t * 256 + lane * 4);
    float v0 = xd.x + b2f(pd.x);
    float v1 = xd.y + b2f(pd.y);
    float v2 = xd.z + b2f(pd.z);
    float v3 = xd.w + b2f(pd.w);
    ushort4 o4;
    o4.x = f2b(v0); o4.y = f2b(v1); o4.z = f2b(v2); o4.w = f2b(v3);
    *(ushort4*)(x2 + loff) = o4;
    float s = v0 + v1 + v2 + v3;
    float ss = v0 * v0 + v1 * v1 + v2 * v2 + v3 * v3;
#pragma unroll
    for (int o = 32; o; o >>= 1) { s += __shfl_xor(s, o, 64); ss += __shfl_xor(ss, o, 64); }
    float mu = s * (1.0f / 256.0f);
    float rs = rsqrtf(ss * (1.0f / 256.0f) - mu * mu + 1e-6f);
    float4 s4 = *(const float4*)(sc + lane * 4);
    float4 b4 = *(const float4*)(bi + lane * 4);
    ushort4 n4;
    n4.x = f2b((v0 - mu) * rs * s4.x + b4.x);
    n4.y = f2b((v1 - mu) * rs * s4.y + b4.y);
    n4.z = f2b((v2 - mu) * rs * s4.z + b4.z);
    n4.w = f2b((v3 - mu) * rs * s4.w + b4.w);
    *(ushort4*)(ln2o + loff) = n4;
}

extern "C" void kernel_launch(void* const* d_in, const int* in_sizes, int n_in,
                              void* d_out, int out_size, void* d_ws, size_t ws_size,
                              hipStream_t stream) {
    const float* x     = (const float*)d_in[0];
    const float* ln1s  = (const float*)d_in[1];
    const float* ln1b  = (const float*)d_in[2];
    const float* qkvw  = (const float*)d_in[3];
    const float* qkvb  = (const float*)d_in[4];
    const float* projw = (const float*)d_in[5];
    const float* projb = (const float*)d_in[6];
    const float* btab  = (const float*)d_in[7];
    const float* ln2s  = (const float*)d_in[8];
    const float* ln2b  = (const float*)d_in[9];
    const float* fc1w  = (const float*)d_in[10];
    const float* fc1b  = (const float*)d_in[11];
    const float* fc2w  = (const float*)d_in[12];
    const float* fc2b  = (const float*)d_in[13];
    float* out = (float*)d_out;                 // FINAL OUTPUT IS FP32
    char* ws = (char*)d_ws;

    // ws: transposed bf16 weights (1.5 MB) + Sadd table (256 KB), then chunk regions.
    u16* wt_qkv  = (u16*)(ws + 0);        // 256x768^T   393216 B
    u16* wt_proj = (u16*)(ws + 393216);   // 256x256^T   131072 B
    u16* wt_fc1  = (u16*)(ws + 524288);   // 256x1024^T  524288 B
    u16* wt_fc2  = (u16*)(ws + 1048576);  // 1024x256^T  524288 B
    u16* saddt   = (u16*)(ws + 1572864);  // [4][8][64][64] bf16 = 262144 B
    const size_t base = 1835008;

    build_sadd<<<512, 256, 0, stream>>>(btab, saddt);
    transpose_k<<<768, 256, 0, stream>>>(qkvw, wt_qkv, 256, 768);
    transpose_k<<<256, 256, 0, stream>>>(projw, wt_proj, 256, 256);
    transpose_k<<<1024, 256, 0, stream>>>(fc1w, wt_fc1, 256, 1024);
    transpose_k<<<1024, 256, 0, stream>>>(fc2w, wt_fc2, 1024, 256);

    int NB = 16;
    while (NB > 1 && base + (size_t)NB * 3136 * 3072 > ws_size) NB >>= 1;
    const size_t T = (size_t)NB * 3136;

    u16* regA = (u16*)(ws + base);                       // T*512  B: win -> attno -> ln2o
    u16* regB = (u16*)(ws + base + T * 512);             // T*2048 B: qkv -> projo -> mlph
    u16* regX = (u16*)(ws + base + T * 512 + T * 2048);  // T*512  B: x2 residual

    for (int c0 = 0; c0 < 32; c0 += NB) {
        size_t tok0 = (size_t)c0 * 3136;
        float* outc = out + tok0 * 256;
        int Mc = (int)T;
        int gx = (Mc + 127) / 128;

        ln1_win_kernel<<<Mc / 4, 256, 0, stream>>>(x, tok0, ln1s, ln1b, regA);
        gemm_bt<0><<<dim3(6, gx), 256, 0, stream>>>(regA, wt_qkv, qkvb, nullptr,
                                                    regB, Mc, 768, 256);
        attn_kernel<<<NB * 128, 256, 0, stream>>>(regB, saddt, regA);
        gemm_bt<0><<<dim3(2, gx), 256, 0, stream>>>(regA, wt_proj, projb, nullptr,
                                                    regB, Mc, 256, 256);
        scatter_ln2_kernel<<<Mc / 4, 256, 0, stream>>>(x, tok0, regB, ln2s, ln2b,
                                                       regX, regA);
        gemm_bt<1><<<dim3(8, gx), 256, 0, stream>>>(regA, wt_fc1, fc1b, nullptr,
                                                    regB, Mc, 1024, 256);
        gemm_bt<2><<<dim3(2, gx), 256, 0, stream>>>(regB, wt_fc2, fc2b, regX,
                                                    outc, Mc, 256, 1024);
    }
}

// Round 6
// 678.843 us; speedup vs baseline: 1.6290x; 1.0374x over previous
//
#include <hip/hip_runtime.h>

typedef unsigned short u16;
typedef short short8v __attribute__((ext_vector_type(8)));
typedef float float4v __attribute__((ext_vector_type(4)));

__device__ __forceinline__ float b2f(u16 u) { return __uint_as_float(((unsigned)u) << 16); }
__device__ __forceinline__ u16 f2b(float f) {
    unsigned i = __float_as_uint(f);
    unsigned r = i + 0x7fffu + ((i >> 16) & 1u);
    return (u16)(r >> 16);
}
// tanh-gelu via hardware exp + fast rcp (1-ulp; noise vs bf16 rounding).
// 0.5x(1+tanh z) = x - x/(e^{2z}+1), exact identity.
__device__ __forceinline__ float gelu_f(float x) {
    float t = x * x;
    float z2 = 1.5957691216057308f * x * __builtin_fmaf(0.044715f, t, 1.0f);
    float e = __expf(z2);
    return x - x * __builtin_amdgcn_rcpf(e + 1.0f);
}

typedef const __attribute__((address_space(1))) unsigned int* gas_ptr;
typedef __attribute__((address_space(3))) unsigned int* las_ptr;
// async global->LDS, 16B per lane, dest = wave-uniform base + lane*16
__device__ __forceinline__ void gload16(const u16* g, u16* l) {
    __builtin_amdgcn_global_load_lds((gas_ptr)g, (las_ptr)l, 16, 0, 0);
}

// out[n*K + k] = bf16(in[k*N + n])   (fp32 weights -> bf16 transposed, k-contiguous)
__global__ void transpose_k(const float* __restrict__ in, u16* __restrict__ out, int K, int N) {
    int idx = blockIdx.x * 256 + threadIdx.x;
    if (idx < K * N) {
        int n = idx / K;
        int k = idx - n * K;
        out[idx] = f2b(in[(size_t)k * N + n]);
    }
}

// Precompute Sadd[type][h][64][64] bf16: rel-pos bias + shift mask + key padding.
// type bit1 = (window row == 7), bit0 = (window col == 7). Keys>=49 => -1e30.
__global__ void build_sadd(const float* __restrict__ btab, u16* __restrict__ tbl) {
    int idx = blockIdx.x * 256 + threadIdx.x;  // 4*8*64*64 = 131072
    int key = idx & 63;
    int q = (idx >> 6) & 63;
    int h = (idx >> 12) & 7;
    int type = idx >> 15;
    float v;
    if (key >= 49 || q >= 49) {
        v = -1e30f;
    } else {
        int qy = q / 7, qx = q - qy * 7;      // query token coords
        int ky = key / 7, kx = key - ky * 7;  // key token coords
        int ridx = (qx - kx + 6) * 13 + (qy - ky + 6);
        v = btab[ridx * 8 + h];
        int rcq = (type & 2) ? (qy < 4 ? 1 : 2) : 0;
        int ccq = (type & 1) ? (qx < 4 ? 1 : 2) : 0;
        int rck = (type & 2) ? (ky < 4 ? 1 : 2) : 0;
        int cck = (type & 1) ? (kx < 4 ? 1 : 2) : 0;
        if (rcq * 3 + ccq != rck * 3 + cck) v += -100.0f;
    }
    tbl[idx] = f2b(v);
}

// LN1 + cyclic shift(-3,-3) + window partition. One wave per windowed token (chunk-local).
__global__ __launch_bounds__(256) void ln1_win_kernel(
    const float* __restrict__ x, size_t tok0, const float* __restrict__ sc,
    const float* __restrict__ bi, u16* __restrict__ win) {
    int t = blockIdx.x * 4 + (threadIdx.x >> 6);
    int lane = threadIdx.x & 63;
    int wi = t / 49, p = t - wi * 49;
    int b = wi >> 6, w = wi & 63;
    int wr = w >> 3, wc = w & 7;
    int ii = p / 7, jj = p - ii * 7;
    int r = wr * 7 + ii + 3; if (r >= 56) r -= 56;
    int c = wc * 7 + jj + 3; if (c >= 56) c -= 56;
    size_t off = (tok0 + (size_t)(b * 3136 + r * 56 + c)) * 256 + lane * 4;
    float4 d = *(const float4*)(x + off);
    float v0 = d.x, v1 = d.y, v2 = d.z, v3 = d.w;
    float s = v0 + v1 + v2 + v3;
    float ss = v0 * v0 + v1 * v1 + v2 * v2 + v3 * v3;
#pragma unroll
    for (int o = 32; o; o >>= 1) { s += __shfl_xor(s, o, 64); ss += __shfl_xor(ss, o, 64); }
    float mu = s * (1.0f / 256.0f);
    float rs = rsqrtf(ss * (1.0f / 256.0f) - mu * mu + 1e-6f);
    float4 s4 = *(const float4*)(sc + lane * 4);
    float4 b4 = *(const float4*)(bi + lane * 4);
    ushort4 o4;
    o4.x = f2b((v0 - mu) * rs * s4.x + b4.x);
    o4.y = f2b((v1 - mu) * rs * s4.y + b4.y);
    o4.z = f2b((v2 - mu) * rs * s4.z + b4.z);
    o4.w = f2b((v3 - mu) * rs * s4.w + b4.w);
    *(ushort4*)(win + (size_t)t * 256 + lane * 4) = o4;
}

// C[M,N] = A[M,K] @ Bt[N,K]^T + bias(fp32), M-guarded. A/Bt bf16.
// EPI: 0 = bias (bf16 out), 1 = bias+gelu (bf16 out), 2 = bias+residual (FP32 out).
// XCD-aware remap: each XCD owns a contiguous slab of m-tiles, n innermost.
// K-loop: prefetch-ahead-2 with counted vmcnt (T4): prologue stages tiles 0,1;
// per iter: vmcnt(8) [only the OLDEST 8 loads = tile kt; tile kt+1 stays in
// flight] -> barrier -> compute(kt) -> barrier -> issue tile kt+2 into the
// buffer just released. Each load gets a full iteration of latency cover.
template <int EPI>
__global__ __launch_bounds__(256) void gemm_bt(
    const u16* __restrict__ A, const u16* __restrict__ Bt, const float* __restrict__ bias,
    const u16* __restrict__ res, void* __restrict__ Cout, int M, int N, int K) {
    // [buf][As 8192 u16 | Bs 8192 u16] = 64 KB; epilogue reuses flat [128][136] u16.
    __shared__ __align__(16) u16 smem[2][16384];
    int tid = threadIdx.x;
    int bidx = blockIdx.x, bidy = blockIdx.y;
    int nn = gridDim.x, nm = gridDim.y;
    if ((nm & 7) == 0) {
        int d = bidy * nn + bidx;
        int x = d & 7, j = d >> 3;
        int mloc = j / nn;
        bidx = j - mloc * nn;
        bidy = x * (nm >> 3) + mloc;
    }
    int m0 = bidy * 128, n0 = bidx * 128;
    int lane = tid & 63, wave = tid >> 6;
    int wm = (wave >> 1) * 64, wn = (wave & 1) * 64;
    int lrow = lane & 15, qd = lane >> 4;
    int c0 = wave << 2;
    int rsub0 = lane >> 3;
    int kc = (((lane & 7) ^ rsub0) << 3);    // swizzled source slot
    float4v acc[4][4] = {};
    int kTiles = K >> 6;

    const u16* Aps[4];
    const u16* Bps[4];
#pragma unroll
    for (int i = 0; i < 4; ++i) {
        int c = c0 + i;
        int rsub = (c << 3) + rsub0;
        int rA = m0 + rsub; if (rA >= M) rA = M - 1;  // clamp; store is guarded
        Aps[i] = A + (size_t)rA * K + kc;
        Bps[i] = Bt + (size_t)(n0 + rsub) * K + kc;
    }
    // prologue: stage tile 0 -> buf0, tile 1 -> buf1 (8 loads each per thread)
#pragma unroll
    for (int i = 0; i < 4; ++i) {
        gload16(Aps[i], &smem[0][(c0 + i) << 9]);
        gload16(Bps[i], &smem[0][8192 + ((c0 + i) << 9)]);
    }
    if (kTiles > 1) {
#pragma unroll
        for (int i = 0; i < 4; ++i) {
            gload16(Aps[i] + 64, &smem[1][(c0 + i) << 9]);
            gload16(Bps[i] + 64, &smem[1][8192 + ((c0 + i) << 9)]);
        }
    }

    for (int kt = 0; kt < kTiles; ++kt) {
        // wait only for tile kt (oldest 8 loads); keep tile kt+1 in flight.
        if (kt + 1 < kTiles)
            asm volatile("s_waitcnt vmcnt(8)" ::: "memory");
        else
            asm volatile("s_waitcnt vmcnt(0)" ::: "memory");
        __builtin_amdgcn_s_barrier();   // all waves' tile-kt data landed
        const u16* As = smem[kt & 1];
        const u16* Bs = smem[kt & 1] + 8192;
#pragma unroll
        for (int ks = 0; ks < 64; ks += 32) {
            short8v af[4], bfr[4];
#pragma unroll
            for (int mi = 0; mi < 4; ++mi) {
                int row = wm + mi * 16 + lrow;
                int s = ((ks >> 3) + qd) ^ (row & 7);          // read-side XOR
                af[mi] = *(const short8v*)&As[row * 64 + (s << 3)];
            }
#pragma unroll
            for (int ni = 0; ni < 4; ++ni) {
                int row = wn + ni * 16 + lrow;
                int s = ((ks >> 3) + qd) ^ (row & 7);
                bfr[ni] = *(const short8v*)&Bs[row * 64 + (s << 3)];
            }
#pragma unroll
            for (int mi = 0; mi < 4; ++mi)
#pragma unroll
                for (int ni = 0; ni < 4; ++ni)
                    acc[mi][ni] = __builtin_amdgcn_mfma_f32_16x16x32_bf16(
                        af[mi], bfr[ni], acc[mi][ni], 0, 0, 0);
        }
        __builtin_amdgcn_s_barrier();   // all reads of buf[kt&1] consumed
        if (kt + 2 < kTiles) {
            int k0 = (kt + 2) << 6;
#pragma unroll
            for (int i = 0; i < 4; ++i) {
                gload16(Aps[i] + k0, &smem[kt & 1][(c0 + i) << 9]);
                gload16(Bps[i] + k0, &smem[kt & 1][8192 + ((c0 + i) << 9)]);
            }
        }
    }
    if (EPI == 2) {
        // fp32 + residual scatter: 16 lanes x 4B = 64B row segments, txn-clean already.
#pragma unroll
        for (int ni = 0; ni < 4; ++ni) {
            int col = n0 + wn + ni * 16 + lrow;
            float bv = bias[col];
#pragma unroll
            for (int mi = 0; mi < 4; ++mi) {
#pragma unroll
                for (int rr = 0; rr < 4; ++rr) {
                    int row = m0 + wm + mi * 16 + qd * 4 + rr;
                    if (row < M) {
                        float v = acc[mi][ni][rr] + bv + b2f(res[(size_t)row * N + col]);
                        ((float*)Cout)[(size_t)row * N + col] = v;
                    }
                }
            }
        }
    } else {
        // bf16 out: transpose-stage via LDS (row stride 136 u16 = 272B: 16B-aligned,
        // write conflicts 2-way=free), then 16B coalesced stores.
        u16* ep = (u16*)smem;
#pragma unroll
        for (int ni = 0; ni < 4; ++ni) {
            float bv = bias[n0 + wn + ni * 16 + lrow];
#pragma unroll
            for (int mi = 0; mi < 4; ++mi) {
#pragma unroll
                for (int rr = 0; rr < 4; ++rr) {
                    float v = acc[mi][ni][rr] + bv;
                    if (EPI == 1) v = gelu_f(v);
                    ep[(wm + mi * 16 + qd * 4 + rr) * 136 + wn + ni * 16 + lrow] = f2b(v);
                }
            }
        }
        __syncthreads();
        u16* outp = (u16*)Cout;
#pragma unroll
        for (int j = 0; j < 8; ++j) {
            int slot = j * 256 + tid;
            int row = slot >> 4, cs = (slot & 15) << 3;
            short8v vv = *(const short8v*)&ep[row * 136 + cs];
            int grow = m0 + row;
            if (grow < M)
                *(short8v*)(outp + (size_t)grow * N + n0 + cs) = vv;
        }
    }
}

// MFMA attention. One wave per (window, head); barrier-free (wave-private LDS).
// S = Q K^T via 16 mfma_16x16x32 (d=32 = one K-step); softmax in C-layout;
// P (bf16, unnormalized) + V^T staged in swizzled LDS; O^T = V^T P^T via 16 mfma;
// 1/rowsum applied at the output.
__global__ __launch_bounds__(256) void attn_kernel(
    const u16* __restrict__ qkv, const u16* __restrict__ sadd, u16* __restrict__ attno) {
    // per wave: P[64][64] u16 swz (8192B) | Vt[32][64] u16 swz (4096B) | sums[64] f32 (256B)
    __shared__ __align__(16) u16 lds[4][6272];  // 50176 B total
    int wave = threadIdx.x >> 6, lane = threadIdx.x & 63;
    u16* Plds = lds[wave];
    u16* Vt = lds[wave] + 4096;
    float* sums = (float*)(lds[wave] + 6144);
    int u = blockIdx.x * 4 + wave;
    int wi = u >> 3, h = u & 7;
    int w = wi & 63;
    int type = (((w >> 3) == 7) ? 2 : 0) | (((w & 7) == 7) ? 1 : 0);
    const u16* base = qkv + (size_t)wi * 49 * 768 + h * 32;
    int lrow = lane & 15, qd = lane >> 4;

    // zero Vt (padded tokens 49..63 must not contain NaN bits), then stage V^T swizzled.
#pragma unroll
    for (int z = 0; z < 4; ++z)
        *(short8v*)&Vt[(z * 64 + lane) * 8] = (short8v){0, 0, 0, 0, 0, 0, 0, 0};
    for (int idx = lane; idx < 196; idx += 64) {
        int t = idx >> 2, part = (idx & 3) << 3;
        uint4 vd = *(const uint4*)(base + 512 + (size_t)t * 768 + part);
        const u16* vs = (const u16*)&vd;
#pragma unroll
        for (int e = 0; e < 8; ++e) {
            int c = part + e;
            Vt[c * 64 + ((((t >> 3) ^ (c & 7)) << 3) | (t & 7))] = vs[e];
        }
    }

    // Q,K fragments straight from global (token-major == fragment layout).
    short8v qf[4], kf[4];
#pragma unroll
    for (int i = 0; i < 4; ++i) {
        qf[i] = *(const short8v*)(base + (size_t)(16 * i + lrow) * 768 + qd * 8);
        kf[i] = *(const short8v*)(base + 256 + (size_t)(16 * i + lrow) * 768 + qd * 8);
    }
    float4v s[4][4];
#pragma unroll
    for (int i = 0; i < 4; ++i)
#pragma unroll
        for (int j = 0; j < 4; ++j)
            s[i][j] = __builtin_amdgcn_mfma_f32_16x16x32_bf16(
                qf[i], kf[j], (float4v){0.f, 0.f, 0.f, 0.f}, 0, 0, 0);

    // scale + bias/mask table; padded-key tile overwritten (kills inf/NaN).
    const float scale = 0.17677669529663687f;  // 32^-0.5
    const u16* tb = sadd + ((size_t)(type * 8 + h) << 12);
#pragma unroll
    for (int i = 0; i < 4; ++i)
#pragma unroll
        for (int j = 0; j < 4; ++j)
#pragma unroll
            for (int rr = 0; rr < 4; ++rr) {
                int q = 16 * i + qd * 4 + rr, key = 16 * j + lrow;
                float v = s[i][j][rr] * scale + b2f(tb[q * 64 + key]);
                if (j == 3 && lrow > 0) v = -1e30f;
                s[i][j][rr] = v;
            }
    // row max (over j-tiles, then 16-lane column group)
    float rmx[4][4];
#pragma unroll
    for (int i = 0; i < 4; ++i)
#pragma unroll
        for (int rr = 0; rr < 4; ++rr) {
            float m = fmaxf(fmaxf(s[i][0][rr], s[i][1][rr]), fmaxf(s[i][2][rr], s[i][3][rr]));
#pragma unroll
            for (int o = 1; o < 16; o <<= 1) m = fmaxf(m, __shfl_xor(m, o, 64));
            rmx[i][rr] = m;
        }
    // exp, row sum, write P (bf16, unnormalized) swizzled
    int hi = lrow >> 3, lo = lrow & 7;
#pragma unroll
    for (int i = 0; i < 4; ++i)
#pragma unroll
        for (int rr = 0; rr < 4; ++rr) {
            int q = 16 * i + qd * 4 + rr;
            float e0 = __expf(s[i][0][rr] - rmx[i][rr]);
            float e1 = __expf(s[i][1][rr] - rmx[i][rr]);
            float e2 = __expf(s[i][2][rr] - rmx[i][rr]);
            float e3 = __expf(s[i][3][rr] - rmx[i][rr]);
            float sm = (e0 + e1) + (e2 + e3);
#pragma unroll
            for (int o = 1; o < 16; o <<= 1) sm += __shfl_xor(sm, o, 64);
            int q64 = q * 64, q7 = q & 7;
            Plds[q64 + ((((0 + hi) ^ q7) << 3) | lo)] = f2b(e0);
            Plds[q64 + ((((2 + hi) ^ q7) << 3) | lo)] = f2b(e1);
            Plds[q64 + ((((4 + hi) ^ q7) << 3) | lo)] = f2b(e2);
            Plds[q64 + ((((6 + hi) ^ q7) << 3) | lo)] = f2b(e3);
            if (lrow == 0) sums[q] = sm;
        }

    // O^T = V^T @ P^T : A-frag = Vt rows (channels), B-frag = P rows (queries as cols).
    float4v o[2][4] = {};
#pragma unroll
    for (int ks = 0; ks < 2; ++ks) {
        short8v av[2], bp[4];
#pragma unroll
        for (int ci = 0; ci < 2; ++ci) {
            int c = 16 * ci + lrow;
            av[ci] = *(const short8v*)&Vt[c * 64 + ((((ks << 2) + qd) ^ (c & 7)) << 3)];
        }
#pragma unroll
        for (int qj = 0; qj < 4; ++qj) {
            int q = 16 * qj + lrow;
            bp[qj] = *(const short8v*)&Plds[q * 64 + ((((ks << 2) + qd) ^ (q & 7)) << 3)];
        }
#pragma unroll
        for (int ci = 0; ci < 2; ++ci)
#pragma unroll
            for (int qj = 0; qj < 4; ++qj)
                o[ci][qj] = __builtin_amdgcn_mfma_f32_16x16x32_bf16(
                    av[ci], bp[qj], o[ci][qj], 0, 0, 0);
    }
    // normalize rows by 1/sum and store: O^T[c][q] -> attno[token q][h*32 + c]
#pragma unroll
    for (int qj = 0; qj < 4; ++qj) {
        int q = 16 * qj + lrow;
        if (q < 49) {
            float inv = __builtin_amdgcn_rcpf(sums[q]);
            u16* op = attno + ((size_t)wi * 49 + q) * 256 + h * 32;
#pragma unroll
            for (int ci = 0; ci < 2; ++ci) {
                ushort4 d4;
                d4.x = f2b(o[ci][qj][0] * inv);
                d4.y = f2b(o[ci][qj][1] * inv);
                d4.z = f2b(o[ci][qj][2] * inv);
                d4.w = f2b(o[ci][qj][3] * inv);
                *(ushort4*)(op + 16 * ci + qd * 4) = d4;
            }
        }
    }
}

// window reverse + roll(+3,+3) + residual + LN2. One wave per natural token (chunk-local).
__global__ __launch_bounds__(256) void scatter_ln2_kernel(
    const float* __restrict__ x, size_t tok0, const u16* __restrict__ projo,
    const float* __restrict__ sc, const float* __restrict__ bi,
    u16* __restrict__ x2, u16* __restrict__ ln2o) {
    int tk = blockIdx.x * 4 + (threadIdx.x >> 6);
    int lane = threadIdx.x & 63;
    int b = tk / 3136, l = tk - b * 3136;
    int r = l / 56, c = l - r * 56;
    int r2 = r + 53; if (r2 >= 56) r2 -= 56;
    int c2 = c + 53; if (c2 >= 56) c2 -= 56;
    int wr = r2 / 7, ri = r2 - wr * 7;
    int wc = c2 / 7, ci = c2 - wc * 7;
    size_t t = ((size_t)(b * 64 + wr * 8 + wc)) * 49 + ri * 7 + ci;
    size_t loff = (size_t)tk * 256 + lane * 4;
    size_t goff = (tok0 + tk) * 256 + lane * 4;
    float4 xd = *(const float4*)(x + goff);
    ushort4 pd = *(const ushort4*)(projo + t * 256 + lane * 4);
    float v0 = xd.x + b2f(pd.x);
    float v1 = xd.y + b2f(pd.y);
    float v2 = xd.z + b2f(pd.z);
    float v3 = xd.w + b2f(pd.w);
    ushort4 o4;
    o4.x = f2b(v0); o4.y = f2b(v1); o4.z = f2b(v2); o4.w = f2b(v3);
    *(ushort4*)(x2 + loff) = o4;
    float s = v0 + v1 + v2 + v3;
    float ss = v0 * v0 + v1 * v1 + v2 * v2 + v3 * v3;
#pragma unroll
    for (int o = 32; o; o >>= 1) { s += __shfl_xor(s, o, 64); ss += __shfl_xor(ss, o, 64); }
    float mu = s * (1.0f / 256.0f);
    float rs = rsqrtf(ss * (1.0f / 256.0f) - mu * mu + 1e-6f);
    float4 s4 = *(const float4*)(sc + lane * 4);
    float4 b4 = *(const float4*)(bi + lane * 4);
    ushort4 n4;
    n4.x = f2b((v0 - mu) * rs * s4.x + b4.x);
    n4.y = f2b((v1 - mu) * rs * s4.y + b4.y);
    n4.z = f2b((v2 - mu) * rs * s4.z + b4.z);
    n4.w = f2b((v3 - mu) * rs * s4.w + b4.w);
    *(ushort4*)(ln2o + loff) = n4;
}

extern "C" void kernel_launch(void* const* d_in, const int* in_sizes, int n_in,
                              void* d_out, int out_size, void* d_ws, size_t ws_size,
                              hipStream_t stream) {
    const float* x     = (const float*)d_in[0];
    const float* ln1s  = (const float*)d_in[1];
    const float* ln1b  = (const float*)d_in[2];
    const float* qkvw  = (const float*)d_in[3];
    const float* qkvb  = (const float*)d_in[4];
    const float* projw = (const float*)d_in[5];
    const float* projb = (const float*)d_in[6];
    const float* btab  = (const float*)d_in[7];
    const float* ln2s  = (const float*)d_in[8];
    const float* ln2b  = (const float*)d_in[9];
    const float* fc1w  = (const float*)d_in[10];
    const float* fc1b  = (const float*)d_in[11];
    const float* fc2w  = (const float*)d_in[12];
    const float* fc2b  = (const float*)d_in[13];
    float* out = (float*)d_out;                 // FINAL OUTPUT IS FP32
    char* ws = (char*)d_ws;

    // ws: transposed bf16 weights (1.5 MB) + Sadd table (256 KB), then chunk regions.
    u16* wt_qkv  = (u16*)(ws + 0);        // 256x768^T   393216 B
    u16* wt_proj = (u16*)(ws + 393216);   // 256x256^T   131072 B
    u16* wt_fc1  = (u16*)(ws + 524288);   // 256x1024^T  524288 B
    u16* wt_fc2  = (u16*)(ws + 1048576);  // 1024x256^T  524288 B
    u16* saddt   = (u16*)(ws + 1572864);  // [4][8][64][64] bf16 = 262144 B
    const size_t base = 1835008;

    build_sadd<<<512, 256, 0, stream>>>(btab, saddt);
    transpose_k<<<768, 256, 0, stream>>>(qkvw, wt_qkv, 256, 768);
    transpose_k<<<256, 256, 0, stream>>>(projw, wt_proj, 256, 256);
    transpose_k<<<1024, 256, 0, stream>>>(fc1w, wt_fc1, 256, 1024);
    transpose_k<<<1024, 256, 0, stream>>>(fc2w, wt_fc2, 1024, 256);

    int NB = 16;
    while (NB > 1 && base + (size_t)NB * 3136 * 3072 > ws_size) NB >>= 1;
    const size_t T = (size_t)NB * 3136;

    u16* regA = (u16*)(ws + base);                       // T*512  B: win -> attno -> ln2o
    u16* regB = (u16*)(ws + base + T * 512);             // T*2048 B: qkv -> projo -> mlph
    u16* regX = (u16*)(ws + base + T * 512 + T * 2048);  // T*512  B: x2 residual

    for (int c0 = 0; c0 < 32; c0 += NB) {
        size_t tok0 = (size_t)c0 * 3136;
        float* outc = out + tok0 * 256;
        int Mc = (int)T;
        int gx = (Mc + 127) / 128;

        ln1_win_kernel<<<Mc / 4, 256, 0, stream>>>(x, tok0, ln1s, ln1b, regA);
        gemm_bt<0><<<dim3(6, gx), 256, 0, stream>>>(regA, wt_qkv, qkvb, nullptr,
                                                    regB, Mc, 768, 256);
        attn_kernel<<<NB * 128, 256, 0, stream>>>(regB, saddt, regA);
        gemm_bt<0><<<dim3(2, gx), 256, 0, stream>>>(regA, wt_proj, projb, nullptr,
                                                    regB, Mc, 256, 256);
        scatter_ln2_kernel<<<Mc / 4, 256, 0, stream>>>(x, tok0, regB, ln2s, ln2b,
                                                       regX, regA);
        gemm_bt<1><<<dim3(8, gx), 256, 0, stream>>>(regA, wt_fc1, fc1b, nullptr,
                                                    regB, Mc, 1024, 256);
        gemm_bt<2><<<dim3(2, gx), 256, 0, stream>>>(regB, wt_fc2, fc2b, regX,
                                                    outc, Mc, 256, 1024);
    }
}

// Round 7
// 676.711 us; speedup vs baseline: 1.6341x; 1.0032x over previous
//
#include <hip/hip_runtime.h>

typedef unsigned short u16;
typedef short short8v __attribute__((ext_vector_type(8)));
typedef float float4v __attribute__((ext_vector_type(4)));

__device__ __forceinline__ float b2f(u16 u) { return __uint_as_float(((unsigned)u) << 16); }
__device__ __forceinline__ u16 f2b(float f) {
    unsigned i = __float_as_uint(f);
    unsigned r = i + 0x7fffu + ((i >> 16) & 1u);
    return (u16)(r >> 16);
}
// tanh-gelu via hardware exp + fast rcp (1-ulp; noise vs bf16 rounding).
__device__ __forceinline__ float gelu_f(float x) {
    float t = x * x;
    float z2 = 1.5957691216057308f * x * __builtin_fmaf(0.044715f, t, 1.0f);
    float e = __expf(z2);
    return x - x * __builtin_amdgcn_rcpf(e + 1.0f);
}

typedef const __attribute__((address_space(1))) unsigned int* gas_ptr;
typedef __attribute__((address_space(3))) unsigned int* las_ptr;
// async global->LDS, 16B per lane, dest = wave-uniform base + lane*16
__device__ __forceinline__ void gload16(const u16* g, u16* l) {
    __builtin_amdgcn_global_load_lds((gas_ptr)g, (las_ptr)l, 16, 0, 0);
}

// out[n*K + k] = bf16(in[k*N + n])   (fp32 weights -> bf16 transposed, k-contiguous)
__global__ void transpose_k(const float* __restrict__ in, u16* __restrict__ out, int K, int N) {
    int idx = blockIdx.x * 256 + threadIdx.x;
    if (idx < K * N) {
        int n = idx / K;
        int k = idx - n * K;
        out[idx] = f2b(in[(size_t)k * N + n]);
    }
}

// Precompute Sadd[type][h][64][64] bf16: rel-pos bias + shift mask + key padding.
__global__ void build_sadd(const float* __restrict__ btab, u16* __restrict__ tbl) {
    int idx = blockIdx.x * 256 + threadIdx.x;  // 4*8*64*64 = 131072
    int key = idx & 63;
    int q = (idx >> 6) & 63;
    int h = (idx >> 12) & 7;
    int type = idx >> 15;
    float v;
    if (key >= 49 || q >= 49) {
        v = -1e30f;
    } else {
        int qy = q / 7, qx = q - qy * 7;
        int ky = key / 7, kx = key - ky * 7;
        int ridx = (qx - kx + 6) * 13 + (qy - ky + 6);
        v = btab[ridx * 8 + h];
        int rcq = (type & 2) ? (qy < 4 ? 1 : 2) : 0;
        int ccq = (type & 1) ? (qx < 4 ? 1 : 2) : 0;
        int rck = (type & 2) ? (ky < 4 ? 1 : 2) : 0;
        int cck = (type & 1) ? (kx < 4 ? 1 : 2) : 0;
        if (rcq * 3 + ccq != rck * 3 + cck) v += -100.0f;
    }
    tbl[idx] = f2b(v);
}

// LN1 + cyclic shift(-3,-3) + window partition. One wave per windowed token (chunk-local).
__global__ __launch_bounds__(256) void ln1_win_kernel(
    const float* __restrict__ x, size_t tok0, const float* __restrict__ sc,
    const float* __restrict__ bi, u16* __restrict__ win) {
    int t = blockIdx.x * 4 + (threadIdx.x >> 6);
    int lane = threadIdx.x & 63;
    int wi = t / 49, p = t - wi * 49;
    int b = wi >> 6, w = wi & 63;
    int wr = w >> 3, wc = w & 7;
    int ii = p / 7, jj = p - ii * 7;
    int r = wr * 7 + ii + 3; if (r >= 56) r -= 56;
    int c = wc * 7 + jj + 3; if (c >= 56) c -= 56;
    size_t off = (tok0 + (size_t)(b * 3136 + r * 56 + c)) * 256 + lane * 4;
    float4 d = *(const float4*)(x + off);
    float v0 = d.x, v1 = d.y, v2 = d.z, v3 = d.w;
    float s = v0 + v1 + v2 + v3;
    float ss = v0 * v0 + v1 * v1 + v2 * v2 + v3 * v3;
#pragma unroll
    for (int o = 32; o; o >>= 1) { s += __shfl_xor(s, o, 64); ss += __shfl_xor(ss, o, 64); }
    float mu = s * (1.0f / 256.0f);
    float rs = rsqrtf(ss * (1.0f / 256.0f) - mu * mu + 1e-6f);
    float4 s4 = *(const float4*)(sc + lane * 4);
    float4 b4 = *(const float4*)(bi + lane * 4);
    ushort4 o4;
    o4.x = f2b((v0 - mu) * rs * s4.x + b4.x);
    o4.y = f2b((v1 - mu) * rs * s4.y + b4.y);
    o4.z = f2b((v2 - mu) * rs * s4.z + b4.z);
    o4.w = f2b((v3 - mu) * rs * s4.w + b4.w);
    *(ushort4*)(win + (size_t)t * 256 + lane * 4) = o4;
}

// C[M,N] = A[M,K] @ Bt[N,K]^T + bias(fp32), M-guarded. A/Bt bf16.
// EPI: 0 = bias (bf16 out), 1 = bias+gelu (bf16 out), 2 = bias+residual (FP32 out).
// XCD-aware remap: each XCD owns a contiguous slab of m-tiles, n innermost.
// BK=32 double-buffer: 16 KB/tile, 2 buffers + 34.8 KB epilogue scratch = ~35 KB
// LDS -> 4 blocks/CU (16 waves) so TLP hides latency (R6 lesson: pipelining
// without occupancy was null). Counted vmcnt(4) keeps next tile in flight.
// Swizzle: LDS slot (row,sl) holds source col-slot sl^((row>>1)&3); read uses
// the same XOR -> per-16-lane group covers 8 distinct 16B slots (2-way = free).
template <int EPI>
__global__ __launch_bounds__(256) void gemm_bt(
    const u16* __restrict__ A, const u16* __restrict__ Bt, const float* __restrict__ bias,
    const u16* __restrict__ res, void* __restrict__ Cout, int M, int N, int K) {
    // buffers: buf k = smem + (k&1)*8192 (As 4096 u16 | Bs 4096 u16).
    // epilogue reuses flat [128][136] u16 = 17408 u16.
    __shared__ __align__(16) u16 smem[17408];
    int tid = threadIdx.x;
    int bidx = blockIdx.x, bidy = blockIdx.y;
    int nn = gridDim.x, nm = gridDim.y;
    if ((nm & 7) == 0) {
        int d = bidy * nn + bidx;
        int x = d & 7, j = d >> 3;
        int mloc = j / nn;
        bidx = j - mloc * nn;
        bidy = x * (nm >> 3) + mloc;
    }
    int m0 = bidy * 128, n0 = bidx * 128;
    int lane = tid & 63, wave = tid >> 6;
    int wm = (wave >> 1) * 64, wn = (wave & 1) * 64;
    int lrow = lane & 15, qd = lane >> 4;
    float4v acc[4][4] = {};
    int kTiles = K >> 5;

    // staging geometry: slot s_lin = j*256 + wave*64 + lane; row = s_lin>>2, sl = lane&3.
    int row0 = wave * 16 + (lane >> 2);          // j=0 row; j=1 row = row0+64
    int swz = (lane & 3) ^ ((row0 >> 1) & 3);    // j-invariant (64j drops out of (row>>1)&3)
    const u16* pA[2];
    const u16* pB[2];
    u16* dA[2];
    u16* dB[2];
#pragma unroll
    for (int j = 0; j < 2; ++j) {
        int row = row0 + 64 * j;
        int rA = m0 + row; if (rA >= M) rA = M - 1;  // clamp; store is guarded
        pA[j] = A + (size_t)rA * K + swz * 8;
        pB[j] = Bt + (size_t)(n0 + row) * K + swz * 8;
        dA[j] = smem + (j * 256 + wave * 64) * 8;        // wave-uniform base
        dB[j] = smem + 4096 + (j * 256 + wave * 64) * 8;
    }
    // prologue: stage tiles 0 (buf0) and 1 (buf1)
#pragma unroll
    for (int j = 0; j < 2; ++j) {
        gload16(pA[j], dA[j]);
        gload16(pB[j], dB[j]);
    }
#pragma unroll
    for (int j = 0; j < 2; ++j) {
        gload16(pA[j] + 32, dA[j] + 8192);
        gload16(pB[j] + 32, dB[j] + 8192);
    }

    for (int kt = 0; kt < kTiles; ++kt) {
        // wait only for tile kt (oldest 4 loads); tile kt+1 stays in flight.
        if (kt + 1 < kTiles)
            asm volatile("s_waitcnt vmcnt(4)" ::: "memory");
        else
            asm volatile("s_waitcnt vmcnt(0)" ::: "memory");
        __builtin_amdgcn_s_barrier();   // all waves' tile-kt data landed
        const u16* As = smem + (kt & 1) * 8192;
        const u16* Bs = As + 4096;
        short8v af[4], bfr[4];
#pragma unroll
        for (int mi = 0; mi < 4; ++mi) {
            int row = wm + mi * 16 + lrow;
            int s = qd ^ ((row >> 1) & 3);
            af[mi] = *(const short8v*)&As[row * 32 + (s << 3)];
        }
#pragma unroll
        for (int ni = 0; ni < 4; ++ni) {
            int row = wn + ni * 16 + lrow;
            int s = qd ^ ((row >> 1) & 3);
            bfr[ni] = *(const short8v*)&Bs[row * 32 + (s << 3)];
        }
#pragma unroll
        for (int mi = 0; mi < 4; ++mi)
#pragma unroll
            for (int ni = 0; ni < 4; ++ni)
                acc[mi][ni] = __builtin_amdgcn_mfma_f32_16x16x32_bf16(
                    af[mi], bfr[ni], acc[mi][ni], 0, 0, 0);
        __builtin_amdgcn_s_barrier();   // all reads of buf[kt&1] consumed
        if (kt + 2 < kTiles) {
            int k0 = (kt + 2) << 5;
            u16* db = smem + (kt & 1) * 8192;
#pragma unroll
            for (int j = 0; j < 2; ++j) {
                gload16(pA[j] + k0, db + (j * 256 + wave * 64) * 8);
                gload16(pB[j] + k0, db + 4096 + (j * 256 + wave * 64) * 8);
            }
        }
    }
    if (EPI == 2) {
        // fp32 + residual scatter: 16 lanes x 4B = 64B row segments, txn-clean already.
#pragma unroll
        for (int ni = 0; ni < 4; ++ni) {
            int col = n0 + wn + ni * 16 + lrow;
            float bv = bias[col];
#pragma unroll
            for (int mi = 0; mi < 4; ++mi) {
#pragma unroll
                for (int rr = 0; rr < 4; ++rr) {
                    int row = m0 + wm + mi * 16 + qd * 4 + rr;
                    if (row < M) {
                        float v = acc[mi][ni][rr] + bv + b2f(res[(size_t)row * N + col]);
                        ((float*)Cout)[(size_t)row * N + col] = v;
                    }
                }
            }
        }
    } else {
        // bf16 out: transpose-stage via LDS (row stride 136 u16 = 272B), then
        // 16B coalesced stores.
#pragma unroll
        for (int ni = 0; ni < 4; ++ni) {
            float bv = bias[n0 + wn + ni * 16 + lrow];
#pragma unroll
            for (int mi = 0; mi < 4; ++mi) {
#pragma unroll
                for (int rr = 0; rr < 4; ++rr) {
                    float v = acc[mi][ni][rr] + bv;
                    if (EPI == 1) v = gelu_f(v);
                    smem[(wm + mi * 16 + qd * 4 + rr) * 136 + wn + ni * 16 + lrow] = f2b(v);
                }
            }
        }
        __syncthreads();
        u16* outp = (u16*)Cout;
#pragma unroll
        for (int j = 0; j < 8; ++j) {
            int slot = j * 256 + tid;
            int row = slot >> 4, cs = (slot & 15) << 3;
            short8v vv = *(const short8v*)&smem[row * 136 + cs];
            int grow = m0 + row;
            if (grow < M)
                *(short8v*)(outp + (size_t)grow * N + n0 + cs) = vv;
        }
    }
}

// MFMA attention. One wave per (window, head); barrier-free (wave-private LDS).
__global__ __launch_bounds__(256) void attn_kernel(
    const u16* __restrict__ qkv, const u16* __restrict__ sadd, u16* __restrict__ attno) {
    // per wave: P[64][64] u16 swz (8192B) | Vt[32][64] u16 swz (4096B) | sums[64] f32 (256B)
    __shared__ __align__(16) u16 lds[4][6272];  // 50176 B total
    int wave = threadIdx.x >> 6, lane = threadIdx.x & 63;
    u16* Plds = lds[wave];
    u16* Vt = lds[wave] + 4096;
    float* sums = (float*)(lds[wave] + 6144);
    int u = blockIdx.x * 4 + wave;
    int wi = u >> 3, h = u & 7;
    int w = wi & 63;
    int type = (((w >> 3) == 7) ? 2 : 0) | (((w & 7) == 7) ? 1 : 0);
    const u16* base = qkv + (size_t)wi * 49 * 768 + h * 32;
    int lrow = lane & 15, qd = lane >> 4;

#pragma unroll
    for (int z = 0; z < 4; ++z)
        *(short8v*)&Vt[(z * 64 + lane) * 8] = (short8v){0, 0, 0, 0, 0, 0, 0, 0};
    for (int idx = lane; idx < 196; idx += 64) {
        int t = idx >> 2, part = (idx & 3) << 3;
        uint4 vd = *(const uint4*)(base + 512 + (size_t)t * 768 + part);
        const u16* vs = (const u16*)&vd;
#pragma unroll
        for (int e = 0; e < 8; ++e) {
            int c = part + e;
            Vt[c * 64 + ((((t >> 3) ^ (c & 7)) << 3) | (t & 7))] = vs[e];
        }
    }

    short8v qf[4], kf[4];
#pragma unroll
    for (int i = 0; i < 4; ++i) {
        qf[i] = *(const short8v*)(base + (size_t)(16 * i + lrow) * 768 + qd * 8);
        kf[i] = *(const short8v*)(base + 256 + (size_t)(16 * i + lrow) * 768 + qd * 8);
    }
    float4v s[4][4];
#pragma unroll
    for (int i = 0; i < 4; ++i)
#pragma unroll
        for (int j = 0; j < 4; ++j)
            s[i][j] = __builtin_amdgcn_mfma_f32_16x16x32_bf16(
                qf[i], kf[j], (float4v){0.f, 0.f, 0.f, 0.f}, 0, 0, 0);

    const float scale = 0.17677669529663687f;  // 32^-0.5
    const u16* tb = sadd + ((size_t)(type * 8 + h) << 12);
#pragma unroll
    for (int i = 0; i < 4; ++i)
#pragma unroll
        for (int j = 0; j < 4; ++j)
#pragma unroll
            for (int rr = 0; rr < 4; ++rr) {
                int q = 16 * i + qd * 4 + rr, key = 16 * j + lrow;
                float v = s[i][j][rr] * scale + b2f(tb[q * 64 + key]);
                if (j == 3 && lrow > 0) v = -1e30f;
                s[i][j][rr] = v;
            }
    float rmx[4][4];
#pragma unroll
    for (int i = 0; i < 4; ++i)
#pragma unroll
        for (int rr = 0; rr < 4; ++rr) {
            float m = fmaxf(fmaxf(s[i][0][rr], s[i][1][rr]), fmaxf(s[i][2][rr], s[i][3][rr]));
#pragma unroll
            for (int o = 1; o < 16; o <<= 1) m = fmaxf(m, __shfl_xor(m, o, 64));
            rmx[i][rr] = m;
        }
    int hi = lrow >> 3, lo = lrow & 7;
#pragma unroll
    for (int i = 0; i < 4; ++i)
#pragma unroll
        for (int rr = 0; rr < 4; ++rr) {
            int q = 16 * i + qd * 4 + rr;
            float e0 = __expf(s[i][0][rr] - rmx[i][rr]);
            float e1 = __expf(s[i][1][rr] - rmx[i][rr]);
            float e2 = __expf(s[i][2][rr] - rmx[i][rr]);
            float e3 = __expf(s[i][3][rr] - rmx[i][rr]);
            float sm = (e0 + e1) + (e2 + e3);
#pragma unroll
            for (int o = 1; o < 16; o <<= 1) sm += __shfl_xor(sm, o, 64);
            int q64 = q * 64, q7 = q & 7;
            Plds[q64 + ((((0 + hi) ^ q7) << 3) | lo)] = f2b(e0);
            Plds[q64 + ((((2 + hi) ^ q7) << 3) | lo)] = f2b(e1);
            Plds[q64 + ((((4 + hi) ^ q7) << 3) | lo)] = f2b(e2);
            Plds[q64 + ((((6 + hi) ^ q7) << 3) | lo)] = f2b(e3);
            if (lrow == 0) sums[q] = sm;
        }

    float4v o[2][4] = {};
#pragma unroll
    for (int ks = 0; ks < 2; ++ks) {
        short8v av[2], bp[4];
#pragma unroll
        for (int ci = 0; ci < 2; ++ci) {
            int c = 16 * ci + lrow;
            av[ci] = *(const short8v*)&Vt[c * 64 + ((((ks << 2) + qd) ^ (c & 7)) << 3)];
        }
#pragma unroll
        for (int qj = 0; qj < 4; ++qj) {
            int q = 16 * qj + lrow;
            bp[qj] = *(const short8v*)&Plds[q * 64 + ((((ks << 2) + qd) ^ (q & 7)) << 3)];
        }
#pragma unroll
        for (int ci = 0; ci < 2; ++ci)
#pragma unroll
            for (int qj = 0; qj < 4; ++qj)
                o[ci][qj] = __builtin_amdgcn_mfma_f32_16x16x32_bf16(
                    av[ci], bp[qj], o[ci][qj], 0, 0, 0);
    }
#pragma unroll
    for (int qj = 0; qj < 4; ++qj) {
        int q = 16 * qj + lrow;
        if (q < 49) {
            float inv = __builtin_amdgcn_rcpf(sums[q]);
            u16* op = attno + ((size_t)wi * 49 + q) * 256 + h * 32;
#pragma unroll
            for (int ci = 0; ci < 2; ++ci) {
                ushort4 d4;
                d4.x = f2b(o[ci][qj][0] * inv);
                d4.y = f2b(o[ci][qj][1] * inv);
                d4.z = f2b(o[ci][qj][2] * inv);
                d4.w = f2b(o[ci][qj][3] * inv);
                *(ushort4*)(op + 16 * ci + qd * 4) = d4;
            }
        }
    }
}

// window reverse + roll(+3,+3) + residual + LN2. One wave per natural token (chunk-local).
__global__ __launch_bounds__(256) void scatter_ln2_kernel(
    const float* __restrict__ x, size_t tok0, const u16* __restrict__ projo,
    const float* __restrict__ sc, const float* __restrict__ bi,
    u16* __restrict__ x2, u16* __restrict__ ln2o) {
    int tk = blockIdx.x * 4 + (threadIdx.x >> 6);
    int lane = threadIdx.x & 63;
    int b = tk / 3136, l = tk - b * 3136;
    int r = l / 56, c = l - r * 56;
    int r2 = r + 53; if (r2 >= 56) r2 -= 56;
    int c2 = c + 53; if (c2 >= 56) c2 -= 56;
    int wr = r2 / 7, ri = r2 - wr * 7;
    int wc = c2 / 7, ci = c2 - wc * 7;
    size_t t = ((size_t)(b * 64 + wr * 8 + wc)) * 49 + ri * 7 + ci;
    size_t loff = (size_t)tk * 256 + lane * 4;
    size_t goff = (tok0 + tk) * 256 + lane * 4;
    float4 xd = *(const float4*)(x + goff);
    ushort4 pd = *(const ushort4*)(projo + t * 256 + lane * 4);
    float v0 = xd.x + b2f(pd.x);
    float v1 = xd.y + b2f(pd.y);
    float v2 = xd.z + b2f(pd.z);
    float v3 = xd.w + b2f(pd.w);
    ushort4 o4;
    o4.x = f2b(v0); o4.y = f2b(v1); o4.z = f2b(v2); o4.w = f2b(v3);
    *(ushort4*)(x2 + loff) = o4;
    float s = v0 + v1 + v2 + v3;
    float ss = v0 * v0 + v1 * v1 + v2 * v2 + v3 * v3;
#pragma unroll
    for (int o = 32; o; o >>= 1) { s += __shfl_xor(s, o, 64); ss += __shfl_xor(ss, o, 64); }
    float mu = s * (1.0f / 256.0f);
    float rs = rsqrtf(ss * (1.0f / 256.0f) - mu * mu + 1e-6f);
    float4 s4 = *(const float4*)(sc + lane * 4);
    float4 b4 = *(const float4*)(bi + lane * 4);
    ushort4 n4;
    n4.x = f2b((v0 - mu) * rs * s4.x + b4.x);
    n4.y = f2b((v1 - mu) * rs * s4.y + b4.y);
    n4.z = f2b((v2 - mu) * rs * s4.z + b4.z);
    n4.w = f2b((v3 - mu) * rs * s4.w + b4.w);
    *(ushort4*)(ln2o + loff) = n4;
}

extern "C" void kernel_launch(void* const* d_in, const int* in_sizes, int n_in,
                              void* d_out, int out_size, void* d_ws, size_t ws_size,
                              hipStream_t stream) {
    const float* x     = (const float*)d_in[0];
    const float* ln1s  = (const float*)d_in[1];
    const float* ln1b  = (const float*)d_in[2];
    const float* qkvw  = (const float*)d_in[3];
    const float* qkvb  = (const float*)d_in[4];
    const float* projw = (const float*)d_in[5];
    const float* projb = (const float*)d_in[6];
    const float* btab  = (const float*)d_in[7];
    const float* ln2s  = (const float*)d_in[8];
    const float* ln2b  = (const float*)d_in[9];
    const float* fc1w  = (const float*)d_in[10];
    const float* fc1b  = (const float*)d_in[11];
    const float* fc2w  = (const float*)d_in[12];
    const float* fc2b  = (const float*)d_in[13];
    float* out = (float*)d_out;                 // FINAL OUTPUT IS FP32
    char* ws = (char*)d_ws;

    // ws: transposed bf16 weights (1.5 MB) + Sadd table (256 KB), then chunk regions.
    u16* wt_qkv  = (u16*)(ws + 0);        // 256x768^T   393216 B
    u16* wt_proj = (u16*)(ws + 393216);   // 256x256^T   131072 B
    u16* wt_fc1  = (u16*)(ws + 524288);   // 256x1024^T  524288 B
    u16* wt_fc2  = (u16*)(ws + 1048576);  // 1024x256^T  524288 B
    u16* saddt   = (u16*)(ws + 1572864);  // [4][8][64][64] bf16 = 262144 B
    const size_t base = 1835008;

    build_sadd<<<512, 256, 0, stream>>>(btab, saddt);
    transpose_k<<<768, 256, 0, stream>>>(qkvw, wt_qkv, 256, 768);
    transpose_k<<<256, 256, 0, stream>>>(projw, wt_proj, 256, 256);
    transpose_k<<<1024, 256, 0, stream>>>(fc1w, wt_fc1, 256, 1024);
    transpose_k<<<1024, 256, 0, stream>>>(fc2w, wt_fc2, 1024, 256);

    int NB = 16;
    while (NB > 1 && base + (size_t)NB * 3136 * 3072 > ws_size) NB >>= 1;
    const size_t T = (size_t)NB * 3136;

    u16* regA = (u16*)(ws + base);                       // T*512  B: win -> attno -> ln2o
    u16* regB = (u16*)(ws + base + T * 512);             // T*2048 B: qkv -> projo -> mlph
    u16* regX = (u16*)(ws + base + T * 512 + T * 2048);  // T*512  B: x2 residual

    for (int c0 = 0; c0 < 32; c0 += NB) {
        size_t tok0 = (size_t)c0 * 3136;
        float* outc = out + tok0 * 256;
        int Mc = (int)T;
        int gx = (Mc + 127) / 128;

        ln1_win_kernel<<<Mc / 4, 256, 0, stream>>>(x, tok0, ln1s, ln1b, regA);
        gemm_bt<0><<<dim3(6, gx), 256, 0, stream>>>(regA, wt_qkv, qkvb, nullptr,
                                                    regB, Mc, 768, 256);
        attn_kernel<<<NB * 128, 256, 0, stream>>>(regB, saddt, regA);
        gemm_bt<0><<<dim3(2, gx), 256, 0, stream>>>(regA, wt_proj, projb, nullptr,
                                                    regB, Mc, 256, 256);
        scatter_ln2_kernel<<<Mc / 4, 256, 0, stream>>>(x, tok0, regB, ln2s, ln2b,
                                                       regX, regA);
        gemm_bt<1><<<dim3(8, gx), 256, 0, stream>>>(regA, wt_fc1, fc1b, nullptr,
                                                    regB, Mc, 1024, 256);
        gemm_bt<2><<<dim3(2, gx), 256, 0, stream>>>(regB, wt_fc2, fc2b, regX,
                                                    outc, Mc, 256, 1024);
    }
}